// Round 1
// baseline (31064.926 us; speedup 1.0000x reference)
//
#include <hip/hip_runtime.h>
#include <math.h>

#define TSTEPS 256
#define CDIM 171
#define XSTR 6400          // 256 (padded x) + 6*1024 (h1,h1',h2,h2',h3,h3')
#define SEQB (TSTEPS*CDIM)

typedef short v8s __attribute__((ext_vector_type(8)));
typedef float v4f __attribute__((ext_vector_type(4)));

static __device__ __forceinline__ unsigned short f2bf(float f) {
  unsigned int u = __float_as_uint(f);
  u += 0x7fffu + ((u >> 16) & 1u);          // RTNE
  return (unsigned short)(u >> 16);
}
static __device__ __forceinline__ float bf2f(unsigned short h) {
  return __uint_as_float(((unsigned int)h) << 16);
}
static __device__ __forceinline__ float sigf(float x) { return 1.0f / (1.0f + expf(-x)); }

// dtype probe (verified in R3): bf16 pairs put a bf16 exponent in bits[14:7]
// of each u32; genuine fp32 puts uniform mantissa bits there.
static __device__ __forceinline__ bool probe_bf16(const unsigned int* w) {
  int c = 0;
  #pragma unroll
  for (int i = 0; i < 8; ++i) {
    unsigned e = (w[i] >> 7) & 0xFFu;
    c += (e >= 90u && e <= 145u) ? 1 : 0;
  }
  return c == 8;
}
static __device__ __forceinline__ float getv(const void* p, bool bf, size_t i) {
  return bf ? bf2f(((const unsigned short*)p)[i]) : ((const float*)p)[i];
}

// ---------------------------------------------------------------------------
// init: seed X, bias sums, zero barrier flags, repack ALL weights into
// K-concatenated canonical bf16 buffers:
//   WL1 [4096][1280] = [wih1 padded to 256 | whh1]
//   WL2/WL3 [4096][2048] = [wih | whh]
//   WDEC [176][1024] = dec_w zero-padded rows
//   XGT  [256][128][256] = bf16 ground-truth x, all t (optional, ws-permitting)
// ---------------------------------------------------------------------------
__global__ __launch_bounds__(256) void init_kernel(
    const void* seq, const void* wih1, const void* whh1,
    const void* bih1, const void* bhh1,
    const void* wih2, const void* whh2, const void* bih2, const void* bhh2,
    const void* wih3, const void* whh3, const void* bih3, const void* bhh3,
    const void* decw,
    unsigned short* __restrict__ X, float* __restrict__ BS,
    unsigned* __restrict__ flags,
    unsigned short* __restrict__ WL1, unsigned short* __restrict__ WL2,
    unsigned short* __restrict__ WL3, unsigned short* __restrict__ WDEC,
    unsigned short* __restrict__ XGT,
    const int* __restrict__ gtp, const int* __restrict__ condp)
{
  const int tid = blockIdx.x * 256 + threadIdx.x;
  const int NT = 2048 * 256;
  const bool bfm = probe_bf16((const unsigned int*)seq);
  int gt = gtp[0];
  const bool p0 = 0 < gt;

  for (int i = tid; i < 128 * XSTR; i += NT) {
    int b = i / XSTR, c = i - b * XSTR;
    unsigned short v = 0;
    if (c < CDIM && p0) v = f2bf(getv(seq, bfm, (size_t)b * SEQB + c));
    X[i] = v;
  }
  const void* bis[3] = {bih1, bih2, bih3};
  const void* bhs[3] = {bhh1, bhh2, bhh3};
  for (int i = tid; i < 3 * 4096; i += NT) {
    int l = i >> 12, n = i & 4095;
    BS[i] = getv(bis[l], bfm, n) + getv(bhs[l], bfm, n);
  }
  for (int i = tid; i < 256; i += NT) flags[i] = 0u;
  for (int i = tid; i < 4096 * 1280; i += NT) {
    int r = i / 1280, c = i - r * 1280;
    float v;
    if (c < CDIM)      v = getv(wih1, bfm, (size_t)r * CDIM + c);
    else if (c < 256)  v = 0.f;
    else               v = getv(whh1, bfm, (size_t)r * 1024 + (c - 256));
    WL1[i] = f2bf(v);
  }
  for (int i = tid; i < 4096 * 2048; i += NT) {
    int r = i >> 11, c = i & 2047;
    size_t o = (size_t)r * 1024 + (c & 1023);
    WL2[i] = f2bf((c < 1024) ? getv(wih2, bfm, o) : getv(whh2, bfm, o));
    WL3[i] = f2bf((c < 1024) ? getv(wih3, bfm, o) : getv(whh3, bfm, o));
  }
  for (int i = tid; i < 176 * 1024; i += NT) {
    int r = i >> 10, c = i & 1023;
    WDEC[i] = (r < CDIM) ? f2bf(getv(decw, bfm, (size_t)r * 1024 + c)) : (unsigned short)0;
  }
  if (XGT) {
    // XGT[t][b][c256]: bf16 seq frame, zero-padded cols 171..255.
    for (int i = tid; i < TSTEPS * 128 * 256; i += NT) {
      int t = i >> 15, b = (i >> 8) & 127, c = i & 255;
      unsigned short v = 0;
      if (c < CDIM) v = f2bf(getv(seq, bfm, (size_t)b * SEQB + (size_t)t * CDIM + c));
      XGT[i] = v;
    }
  }
}

// ---------------------------------------------------------------------------
// Grid barrier: flag-array + all-poll (no contended fetch_add). Thread0
// release-stores its WG's flag AFTER __syncthreads (whose implicit
// s_waitcnt vmcnt(0) drains all WG stores to L2); the RELEASE store itself
// carries the agent-scope L2 writeback for cross-XCD visibility (no extra
// __threadfence — that was a duplicate wbl2+inv). Wave0 polls all 256
// flags, 4 per lane; lane0's acquire fence invalidates L1/L2 before the
// phase's X reads. Works for any co-resident grid (256 WGs @ 1/CU here).
// ---------------------------------------------------------------------------
static __device__ __forceinline__ void gbar(unsigned* fl, int g, unsigned tgt,
                                            int wave, int lane) {
  __syncthreads();
  if (threadIdx.x == 0) {
    __hip_atomic_store(fl + g, tgt, __ATOMIC_RELEASE, __HIP_MEMORY_SCOPE_AGENT);
  }
  if (wave == 0) {
    for (;;) {
      unsigned a = __hip_atomic_load(fl + lane,       __ATOMIC_RELAXED, __HIP_MEMORY_SCOPE_AGENT);
      unsigned b = __hip_atomic_load(fl + 64 + lane,  __ATOMIC_RELAXED, __HIP_MEMORY_SCOPE_AGENT);
      unsigned c = __hip_atomic_load(fl + 128 + lane, __ATOMIC_RELAXED, __HIP_MEMORY_SCOPE_AGENT);
      unsigned d = __hip_atomic_load(fl + 192 + lane, __ATOMIC_RELAXED, __HIP_MEMORY_SCOPE_AGENT);
      if (__all((a >= tgt) & (b >= tgt) & (c >= tgt) & (d >= tgt))) break;
      __builtin_amdgcn_s_sleep(1);
    }
    if (lane == 0) __threadfence();
  }
  __syncthreads();
}

// MFMA phase: wave's K-slice against register-resident B frags, 8 M-tiles.
// A cols map through [a0 | a1] split at bnd (activation double-banking).
template<int NCH>
static __device__ __forceinline__ void mfma_phase(
    const v8s* wf, const unsigned short* __restrict__ Xb,
    int a0, int bnd, int a1, int kbase, v4f* acc)
{
  #pragma unroll
  for (int i = 0; i < 8; ++i) acc[i] = (v4f){0.f, 0.f, 0.f, 0.f};
  #pragma unroll
  for (int c = 0; c < NCH; ++c) {
    const int acol = kbase + 32 * c;
    const int xcol = (acol < bnd) ? (a0 + acol) : (a1 + acol - bnd);
    const unsigned short* ap = Xb + xcol;
    #pragma unroll
    for (int m = 0; m < 8; ++m) {
      v8s a = *(const v8s*)(ap + (size_t)(16 * m) * XSTR);
      acc[m] = __builtin_amdgcn_mfma_f32_16x16x32_bf16(a, wf[c], acc[m], 0, 0, 0);
    }
  }
}

// LDS 4-way K-reduce + register-local gate math + bf16 h store.
// NOTE: no trailing __syncthreads — every call site is followed by a gbar
// whose leading __syncthreads provides the lred WAR protection.
static __device__ __forceinline__ void lstm_epilogue(
    v4f* acc, float* lred, int wave, int lane,
    const float* bs4, float* cst2,
    unsigned short* __restrict__ X, int hoff, int g)
{
  const int l15 = lane & 15, quad = lane >> 4;
  float* myp = lred + wave * 2048;
  #pragma unroll
  for (int m = 0; m < 8; ++m)
    #pragma unroll
    for (int j = 0; j < 4; ++j)
      myp[m * 256 + (4 * quad + j) * 16 + l15] = acc[m][j];
  __syncthreads();
  const int ri = lane >> 2, hc = lane & 3;
  #pragma unroll
  for (int e = 0; e < 2; ++e) {
    const int m = 2 * wave + e;
    float z0 = bs4[0], z1 = bs4[1], z2 = bs4[2], z3 = bs4[3];
    #pragma unroll
    for (int w2 = 0; w2 < 4; ++w2) {
      const float* pp = lred + w2 * 2048 + m * 256 + ri * 16 + hc;
      z0 += pp[0]; z1 += pp[4]; z2 += pp[8]; z3 += pp[12];
    }
    float cn = sigf(z1) * cst2[e] + sigf(z0) * tanhf(z2);
    float h  = sigf(z3) * tanhf(cn);
    cst2[e] = cn;
    const int row = 32 * wave + 16 * e + ri;
    X[(size_t)row * XSTR + hoff + 4 * g + hc] = f2bf(h);
  }
}

// ---------------------------------------------------------------------------
// Persistent kernel (PLAIN launch; co-resident by construction: 32KB LDS,
// <=512 VGPR -> every CU hosts >=1 WG, grid 256 = capacity). WG g owns
// h-cols [4g,4g+4) of every layer (16 z-cols = 4 hcols x 4 gates; B-row for
// tile col n is 1024*(n>>2) + 4g + (n&3)). Waves K-split 4-way; all weights
// VGPR-resident (loaded once); c-state in registers.
//
// Barrier schedule: gbar2 (L1->L2), gbar3 (L2->L3), gbar4 (L3->dec) every
// step; gbar1 (dec(t-1)->L1(t)) ONLY on self-fed steps (pattern(t)==false,
// t>0) — on ground-truth steps x(t) comes straight from seq (via prepacked
// XGT if workspace allows, else per-element), so the dec output is not an
// input and the barrier is elided (~1/8 of all barriers at gt=cond=5).
// ---------------------------------------------------------------------------
__global__ __launch_bounds__(256, 1) void persist(
    const unsigned short* __restrict__ WL1, const unsigned short* __restrict__ WL2,
    const unsigned short* __restrict__ WL3, const unsigned short* __restrict__ WDEC,
    const float* __restrict__ BS, unsigned short* __restrict__ X,
    unsigned* __restrict__ flags,
    const void* __restrict__ seq, const void* __restrict__ decb,
    void* __restrict__ outp, const unsigned short* __restrict__ XGT,
    const int* __restrict__ gtp, const int* __restrict__ condp)
{
  const int g = blockIdx.x;
  const int tid = threadIdx.x, wave = tid >> 6, lane = tid & 63;
  const int l15 = lane & 15, quad = lane >> 4;
  const bool bf = probe_bf16((const unsigned int*)seq);
  int gt = gtp[0]; int per = gt + condp[0]; if (per < 1) per = 1;

  const int br = 1024 * (l15 >> 2) + 4 * g + (l15 & 3);
  v8s w1f[10], w2f[16], w3f[16], wdf[8];
  {
    const unsigned short* p = WL1 + (size_t)br * 1280 + 320 * wave + 8 * quad;
    #pragma unroll
    for (int c = 0; c < 10; ++c) w1f[c] = *(const v8s*)(p + 32 * c);
  }
  {
    const unsigned short* p = WL2 + (size_t)br * 2048 + 512 * wave + 8 * quad;
    #pragma unroll
    for (int c = 0; c < 16; ++c) w2f[c] = *(const v8s*)(p + 32 * c);
  }
  {
    const unsigned short* p = WL3 + (size_t)br * 2048 + 512 * wave + 8 * quad;
    #pragma unroll
    for (int c = 0; c < 16; ++c) w3f[c] = *(const v8s*)(p + 32 * c);
  }
  const int dm = g / 11, dn = g - dm * 11;
  if (g < 88) {
    const unsigned short* p = WDEC + (size_t)(16 * dn + l15) * 1024 + 256 * wave + 8 * quad;
    #pragma unroll
    for (int c = 0; c < 8; ++c) wdf[c] = *(const v8s*)(p + 32 * c);
  } else {
    #pragma unroll
    for (int c = 0; c < 8; ++c) wdf[c] = (v8s){0, 0, 0, 0, 0, 0, 0, 0};
  }
  float bsr[3][4];
  #pragma unroll
  for (int l = 0; l < 3; ++l)
    #pragma unroll
    for (int gm = 0; gm < 4; ++gm)
      bsr[l][gm] = BS[4096 * l + 1024 * gm + 4 * g + (lane & 3)];
  float dbv = 0.f;
  if (g < 88) { int col = 16 * dn + l15; if (col < CDIM) dbv = getv(decb, bf, col); }

  float cst1[2] = {0.f, 0.f}, cst2v[2] = {0.f, 0.f}, cst3[2] = {0.f, 0.f};
  __shared__ float lred[8192];                       // [4 waves][8 tiles][16][16]
  const unsigned short* Xb = X + (size_t)l15 * XSTR + 8 * quad;   // lane A-base
  unsigned bgen = 0;
  v4f acc[8];

  for (int t = 0; t < TSTEPS; ++t) {
    const int p_ = t & 1, q_ = p_ ^ 1;
    const bool pt = (t % per) < gt;                  // ground-truth step?
    if (t > 0 && !pt) gbar(flags, g, ++bgen, wave, lane);  // dec(t-1) -> L1(t)

    // ---- L1 ----
    if (pt && wave == 0) {
      // wave0's K-slice covers the x-cols: chains 0..7 read seq directly
      // (no barrier dependency on dec), chains 8..9 read h1(t-1) from X.
      #pragma unroll
      for (int i = 0; i < 8; ++i) acc[i] = (v4f){0.f, 0.f, 0.f, 0.f};
      if (XGT) {
        const unsigned short* xb = XGT + ((size_t)t * 128 + l15) * 256 + 8 * quad;
        #pragma unroll
        for (int c = 0; c < 8; ++c) {
          #pragma unroll
          for (int m = 0; m < 8; ++m) {
            v8s a = *(const v8s*)(xb + 32 * c + (size_t)(16 * m) * 256);
            acc[m] = __builtin_amdgcn_mfma_f32_16x16x32_bf16(a, w1f[c], acc[m], 0, 0, 0);
          }
        }
      } else {
        #pragma unroll
        for (int c = 0; c < 8; ++c) {
          const int col0 = 32 * c + 8 * quad;
          #pragma unroll
          for (int m = 0; m < 8; ++m) {
            const size_t so = (size_t)(l15 + 16 * m) * SEQB + (size_t)t * CDIM;
            v8s a;
            #pragma unroll
            for (int j = 0; j < 8; ++j) {
              const int cc = col0 + j;
              unsigned short hv = 0;
              if (cc < CDIM)
                hv = bf ? ((const unsigned short*)seq)[so + cc]
                        : f2bf(((const float*)seq)[so + cc]);
              a[j] = (short)hv;
            }
            acc[m] = __builtin_amdgcn_mfma_f32_16x16x32_bf16(a, w1f[c], acc[m], 0, 0, 0);
          }
        }
      }
      #pragma unroll
      for (int c = 8; c < 10; ++c) {
        const unsigned short* ap = Xb + (256 + 1024 * q_) + (32 * c - 256);
        #pragma unroll
        for (int m = 0; m < 8; ++m) {
          v8s a = *(const v8s*)(ap + (size_t)(16 * m) * XSTR);
          acc[m] = __builtin_amdgcn_mfma_f32_16x16x32_bf16(a, w1f[c], acc[m], 0, 0, 0);
        }
      }
    } else {
      mfma_phase<10>(w1f, Xb, 0, 256, 256 + 1024 * q_, 320 * wave, acc);
    }
    lstm_epilogue(acc, lred, wave, lane, bsr[0], cst1, X, 256 + 1024 * p_, g);

    gbar(flags, g, ++bgen, wave, lane);
    mfma_phase<16>(w2f, Xb, 256 + 1024 * p_, 1024, 2304 + 1024 * q_, 512 * wave, acc);
    lstm_epilogue(acc, lred, wave, lane, bsr[1], cst2v, X, 2304 + 1024 * p_, g);

    gbar(flags, g, ++bgen, wave, lane);
    mfma_phase<16>(w3f, Xb, 2304 + 1024 * p_, 1024, 4352 + 1024 * q_, 512 * wave, acc);
    lstm_epilogue(acc, lred, wave, lane, bsr[2], cst3, X, 4352 + 1024 * p_, g);

    gbar(flags, g, ++bgen, wave, lane);              // L3 -> dec
    if (g < 88) {
      v4f da = (v4f){0.f, 0.f, 0.f, 0.f};
      const unsigned short* ap = X + (size_t)(16 * dm + l15) * XSTR
                               + (4352 + 1024 * p_) + 256 * wave + 8 * quad;
      #pragma unroll
      for (int c = 0; c < 8; ++c) {
        v8s a = *(const v8s*)(ap + 32 * c);
        da = __builtin_amdgcn_mfma_f32_16x16x32_bf16(a, wdf[c], da, 0, 0, 0);
      }
      float* myp = lred + wave * 2048;
      #pragma unroll
      for (int j = 0; j < 4; ++j) myp[(4 * quad + j) * 16 + l15] = da[j];
      __syncthreads();
      if (wave == 0) {
        const int col = 16 * dn + l15;
        const bool pnext = ((t + 1) % per) < gt;
        #pragma unroll
        for (int e = 0; e < 4; ++e) {
          const int r = 4 * e + quad;
          float v = dbv;
          #pragma unroll
          for (int w2 = 0; w2 < 4; ++w2) v += lred[w2 * 2048 + r * 16 + l15];
          if (col < CDIM) {
            const int brow = 16 * dm + r;
            const size_t oidx = (size_t)brow * SEQB + (size_t)t * CDIM + col;
            if (bf) ((unsigned short*)outp)[oidx] = f2bf(v);
            else    ((float*)outp)[oidx] = v;
            // Self-fed next frame only: ground-truth frames are read
            // straight from seq/XGT by L1, so no X writeback (and no
            // gbar1) is needed for them.
            if (t < TSTEPS - 1 && !pnext)
              X[(size_t)brow * XSTR + col] = f2bf(v);
          }
        }
      }
      __syncthreads();   // protect lred reads: next L1 epilogue may follow
                         // WITHOUT an intervening gbar (skipped on gt steps)
    }
  }
}

// ---------------------------------------------------------------------------
// Workspace (bytes, total ~62.9 MB; XGT used only if ws_size permits):
//   X     @ 0         : [128][6400] bf16
//   BS    @ 1638400   : [3][4096] fp32
//   FLAGS @ 1687552   : [256] u32 barrier flags
//   WL1   @ 1690624   : [4096][1280] bf16
//   WL2   @ 12176384  : [4096][2048] bf16
//   WL3   @ 28953600  : [4096][2048] bf16
//   WDEC  @ 45730816  : [176][1024] bf16
//   XGT   @ 46091264  : [256][128][256] bf16 (optional, 16.8 MB)
// ---------------------------------------------------------------------------
extern "C" void kernel_launch(void* const* d_in, const int* in_sizes, int n_in,
                              void* d_out, int out_size, void* d_ws, size_t ws_size,
                              hipStream_t stream) {
  const void* seq  = d_in[0];
  const void* wih1 = d_in[1];  const void* whh1 = d_in[2];
  const void* bih1 = d_in[3];  const void* bhh1 = d_in[4];
  const void* wih2 = d_in[5];  const void* whh2 = d_in[6];
  const void* bih2 = d_in[7];  const void* bhh2 = d_in[8];
  const void* wih3 = d_in[9];  const void* whh3 = d_in[10];
  const void* bih3 = d_in[11]; const void* bhh3 = d_in[12];
  const void* decw = d_in[13]; const void* decb = d_in[14];
  const int* gtp   = (const int*)d_in[15];
  const int* condp = (const int*)d_in[16];

  char* ws = (char*)d_ws;
  unsigned short* X    = (unsigned short*)(ws + 0);
  float*          BS   = (float*)(ws + 1638400);
  unsigned*       FLAGS= (unsigned*)(ws + 1687552);
  unsigned short* WL1  = (unsigned short*)(ws + 1690624);
  unsigned short* WL2  = (unsigned short*)(ws + 12176384);
  unsigned short* WL3  = (unsigned short*)(ws + 28953600);
  unsigned short* WDEC = (unsigned short*)(ws + 45730816);
  unsigned short* XGT  = (ws_size >= (size_t)46091264 + (size_t)16777216)
                       ? (unsigned short*)(ws + 46091264) : (unsigned short*)0;

  init_kernel<<<2048, 256, 0, stream>>>(seq, wih1, whh1, bih1, bhh1,
                                        wih2, whh2, bih2, bhh2,
                                        wih3, whh3, bih3, bhh3, decw,
                                        X, BS, FLAGS, WL1, WL2, WL3, WDEC,
                                        XGT, gtp, condp);

  persist<<<256, 256, 0, stream>>>(WL1, WL2, WL3, WDEC, BS, X, FLAGS,
                                   seq, decb, d_out, XGT, gtp, condp);
}

// Round 3
// 21206.285 us; speedup vs baseline: 1.4649x; 1.4649x over previous
//
#include <hip/hip_runtime.h>
#include <math.h>

#define TSTEPS 256
#define CDIM 171
#define XSTR 6400          // 256 (padded x) + 6*1024 (h1,h1',h2,h2',h3,h3')
#define SEQB (TSTEPS*CDIM)

// FLAGS region layout (u32 indices)
#define ARR_OFF   0        // [8][256] per-XCD arrival flags (xcd*256 + rank)
#define GF_OFF    2048     // [8] cross-XCD leader flags, stride 64 (256B pad)
#define REL_OFF   2560     // [8] per-XCD release words, stride 64
#define XCNT_OFF  3072     // [8] per-XCD WG counts
#define GREG_OFF  3080     // [1] global registration count
#define NFLAGS    4096

typedef short v8s __attribute__((ext_vector_type(8)));
typedef float v4f __attribute__((ext_vector_type(4)));

static __device__ __forceinline__ unsigned short f2bf(float f) {
  unsigned int u = __float_as_uint(f);
  u += 0x7fffu + ((u >> 16) & 1u);          // RTNE
  return (unsigned short)(u >> 16);
}
static __device__ __forceinline__ float bf2f(unsigned short h) {
  return __uint_as_float(((unsigned int)h) << 16);
}
static __device__ __forceinline__ float sigf(float x) { return 1.0f / (1.0f + expf(-x)); }

// dtype probe (verified in R3): bf16 pairs put a bf16 exponent in bits[14:7]
// of each u32; genuine fp32 puts uniform mantissa bits there.
static __device__ __forceinline__ bool probe_bf16(const unsigned int* w) {
  int c = 0;
  #pragma unroll
  for (int i = 0; i < 8; ++i) {
    unsigned e = (w[i] >> 7) & 0xFFu;
    c += (e >= 90u && e <= 145u) ? 1 : 0;
  }
  return c == 8;
}
static __device__ __forceinline__ float getv(const void* p, bool bf, size_t i) {
  return bf ? bf2f(((const unsigned short*)p)[i]) : ((const float*)p)[i];
}

static __device__ __forceinline__ unsigned ld_agent(const unsigned* p) {
  return __hip_atomic_load(p, __ATOMIC_RELAXED, __HIP_MEMORY_SCOPE_AGENT);
}
static __device__ __forceinline__ void st_agent(unsigned* p, unsigned v) {
  __hip_atomic_store(p, v, __ATOMIC_RELAXED, __HIP_MEMORY_SCOPE_AGENT);
}

// ---------------------------------------------------------------------------
// init: seed X, bias sums, zero flags, repack ALL weights into K-concatenated
// canonical bf16 buffers:
//   WL1 [4096][1280] = [wih1 padded to 256 | whh1]
//   WL2/WL3 [4096][2048] = [wih | whh]
//   WDEC [176][1024] = dec_w zero-padded rows
//   XGT  [256][128][256] = bf16 ground-truth x, all t (optional, ws-permitting)
// ---------------------------------------------------------------------------
__global__ __launch_bounds__(256) void init_kernel(
    const void* seq, const void* wih1, const void* whh1,
    const void* bih1, const void* bhh1,
    const void* wih2, const void* whh2, const void* bih2, const void* bhh2,
    const void* wih3, const void* whh3, const void* bih3, const void* bhh3,
    const void* decw,
    unsigned short* __restrict__ X, float* __restrict__ BS,
    unsigned* __restrict__ flags,
    unsigned short* __restrict__ WL1, unsigned short* __restrict__ WL2,
    unsigned short* __restrict__ WL3, unsigned short* __restrict__ WDEC,
    unsigned short* __restrict__ XGT,
    const int* __restrict__ gtp, const int* __restrict__ condp)
{
  const int tid = blockIdx.x * 256 + threadIdx.x;
  const int NT = 2048 * 256;
  const bool bfm = probe_bf16((const unsigned int*)seq);
  int gt = gtp[0];
  const bool p0 = 0 < gt;

  for (int i = tid; i < 128 * XSTR; i += NT) {
    int b = i / XSTR, c = i - b * XSTR;
    unsigned short v = 0;
    if (c < CDIM && p0) v = f2bf(getv(seq, bfm, (size_t)b * SEQB + c));
    X[i] = v;
  }
  const void* bis[3] = {bih1, bih2, bih3};
  const void* bhs[3] = {bhh1, bhh2, bhh3};
  for (int i = tid; i < 3 * 4096; i += NT) {
    int l = i >> 12, n = i & 4095;
    BS[i] = getv(bis[l], bfm, n) + getv(bhs[l], bfm, n);
  }
  for (int i = tid; i < NFLAGS; i += NT) flags[i] = 0u;
  for (int i = tid; i < 4096 * 1280; i += NT) {
    int r = i / 1280, c = i - r * 1280;
    float v;
    if (c < CDIM)      v = getv(wih1, bfm, (size_t)r * CDIM + c);
    else if (c < 256)  v = 0.f;
    else               v = getv(whh1, bfm, (size_t)r * 1024 + (c - 256));
    WL1[i] = f2bf(v);
  }
  for (int i = tid; i < 4096 * 2048; i += NT) {
    int r = i >> 11, c = i & 2047;
    size_t o = (size_t)r * 1024 + (c & 1023);
    WL2[i] = f2bf((c < 1024) ? getv(wih2, bfm, o) : getv(whh2, bfm, o));
    WL3[i] = f2bf((c < 1024) ? getv(wih3, bfm, o) : getv(whh3, bfm, o));
  }
  for (int i = tid; i < 176 * 1024; i += NT) {
    int r = i >> 10, c = i & 1023;
    WDEC[i] = (r < CDIM) ? f2bf(getv(decw, bfm, (size_t)r * 1024 + c)) : (unsigned short)0;
  }
  if (XGT) {
    // XGT[t][b][c256]: bf16 seq frame, zero-padded cols 171..255.
    for (int i = tid; i < TSTEPS * 128 * 256; i += NT) {
      int t = i >> 15, b = (i >> 8) & 127, c = i & 255;
      unsigned short v = 0;
      if (c < CDIM) v = f2bf(getv(seq, bfm, (size_t)b * SEQB + (size_t)t * CDIM + c));
      XGT[i] = v;
    }
  }
}

// ---------------------------------------------------------------------------
// Hierarchical grid barrier (R3): exactly ONE buffer_wbl2 + ONE buffer_inv
// (agent/L2 scope) per XCD per barrier, executed by the XCD's leader WG
// (registration rank 0 on its physical XCD via s_getreg XCC_ID). All FLAGS
// traffic is agent-scope atomics (MALL) so visibility never depends on the
// XCD grouping being physically right (hang-proof); only the CACHE
// MAINTENANCE is delegated to leaders. Non-leaders do a cheap L1-only
// buffer_inv after release (their XCD's L2 was invalidated by the leader's
// acquire fence). Removes the ~32x per-XCD serialization of wbl2/inv in the
// old flat barrier (~30us/barrier measured R1).
//
// Protocol per generation G:
//   all WGs : __syncthreads (implicit vmcnt0 -> all my stores are in my L2)
//             thread0 agent-stores arr[xcd][rank]=G    (MALL)
//   leader  : poll all NX arrivals >= G                (MALL)
//             fence(release,agent)                     (wbl2: XCD L2 -> MALL)
//             agent-store gf[xcd]=G                    (MALL)
//             poll gf[k]>=G for active XCDs            (MALL, 8 words)
//             fence(acquire,agent)                     (inv: drop stale L1+L2)
//             agent-store rel[xcd]=G                   (MALL)
//   others  : poll rel[xcd]>=G, then buffer_inv        (L1-only invalidate)
//
// WATCHDOG: 'budget' caps total poll iterations across the whole kernel
// (~100x normal usage). A genuine deadlock converts into a fast wrong-answer
// finish (passed:false + counters) instead of an opaque harness timeout.
// ---------------------------------------------------------------------------
static __device__ __forceinline__ void gbarH(
    unsigned* fl, unsigned xcd, unsigned rank, unsigned NX, unsigned amask,
    unsigned G, int wave, int lane, unsigned& budget)
{
  __syncthreads();
  if (threadIdx.x == 0) st_agent(fl + ARR_OFF + xcd * 256 + rank, G);
  if (wave == 0) {
    if (rank == 0) {
      const unsigned* ab = fl + ARR_OFF + xcd * 256;
      for (;;) {
        unsigned ok = 1u;
        #pragma unroll
        for (int k = 0; k < 4; ++k) {
          unsigned r = (unsigned)lane + 64u * k;
          if (r < NX) ok &= (ld_agent(ab + r) >= G) ? 1u : 0u;
        }
        if (__all((int)ok)) break;
        if (budget == 0) break;
        --budget; __builtin_amdgcn_s_sleep(1);
      }
      __builtin_amdgcn_fence(__ATOMIC_RELEASE, "agent");       // wbl2 sc1
      st_agent(fl + GF_OFF + xcd * 64, G);
      for (;;) {
        unsigned ok = 1u;
        if (lane < 8 && ((amask >> lane) & 1u))
          ok = (ld_agent(fl + GF_OFF + (unsigned)lane * 64) >= G) ? 1u : 0u;
        if (__all((int)ok)) break;
        if (budget == 0) break;
        --budget; __builtin_amdgcn_s_sleep(1);
      }
      __builtin_amdgcn_fence(__ATOMIC_ACQUIRE, "agent");       // inv sc1 (L1+L2)
      st_agent(fl + REL_OFF + xcd * 64, G);
    } else {
      unsigned* rp = fl + REL_OFF + xcd * 64;
      for (;;) {
        unsigned v = ld_agent(rp);
        if (__all((int)(v >= G))) break;
        if (budget == 0) break;
        --budget; __builtin_amdgcn_s_sleep(1);
      }
      asm volatile("buffer_inv" ::: "memory");                 // L1-only inv
    }
  }
  __syncthreads();
}

// MFMA phase: wave's K-slice against register-resident B frags, 8 M-tiles.
// A cols map through [a0 | a1] split at bnd (activation double-banking).
template<int NCH>
static __device__ __forceinline__ void mfma_phase(
    const v8s* wf, const unsigned short* __restrict__ Xb,
    int a0, int bnd, int a1, int kbase, v4f* acc)
{
  #pragma unroll
  for (int i = 0; i < 8; ++i) acc[i] = (v4f){0.f, 0.f, 0.f, 0.f};
  #pragma unroll
  for (int c = 0; c < NCH; ++c) {
    const int acol = kbase + 32 * c;
    const int xcol = (acol < bnd) ? (a0 + acol) : (a1 + acol - bnd);
    const unsigned short* ap = Xb + xcol;
    #pragma unroll
    for (int m = 0; m < 8; ++m) {
      v8s a = *(const v8s*)(ap + (size_t)(16 * m) * XSTR);
      acc[m] = __builtin_amdgcn_mfma_f32_16x16x32_bf16(a, wf[c], acc[m], 0, 0, 0);
    }
  }
}

// LDS 4-way K-reduce + register-local gate math + bf16 h store.
// lred addressing: col-major with XOR swizzle, addr = m*256 + col*16 +
// (row ^ ((col>>1)&3)). Both the fragment stores (fixed m,j: lanes quad,l15)
// and the reduce reads (fixed k: lanes ri,hc) land exactly 2 lanes/bank =
// conflict-free on 64 lanes/32 banks (2-way aliasing is free, m136).
// Old row-major layout was 4-way (stores) / 8-way (reads): 2.0e8 conflicts.
// NOTE: no trailing __syncthreads — every call site is followed by a gbarH
// whose leading __syncthreads provides the lred WAR protection.
static __device__ __forceinline__ void lstm_epilogue(
    v4f* acc, float* lred, int wave, int lane,
    const float* bs4, float* cst2,
    unsigned short* __restrict__ X, int hoff, int g)
{
  const int l15 = lane & 15, quad = lane >> 4;
  float* myp = lred + wave * 2048;
  #pragma unroll
  for (int m = 0; m < 8; ++m)
    #pragma unroll
    for (int j = 0; j < 4; ++j)
      myp[m * 256 + l15 * 16 + ((4 * quad + j) ^ ((l15 >> 1) & 3))] = acc[m][j];
  __syncthreads();
  const int ri = lane >> 2, hc = lane & 3;
  #pragma unroll
  for (int e = 0; e < 2; ++e) {
    const int m = 2 * wave + e;
    float z[4];
    #pragma unroll
    for (int k = 0; k < 4; ++k) z[k] = bs4[k];
    #pragma unroll
    for (int w2 = 0; w2 < 4; ++w2) {
      const float* pp = lred + w2 * 2048 + m * 256;
      #pragma unroll
      for (int k = 0; k < 4; ++k) {
        const int col = hc + 4 * k;
        z[k] += pp[col * 16 + (ri ^ ((col >> 1) & 3))];
      }
    }
    float cn = sigf(z[1]) * cst2[e] + sigf(z[0]) * tanhf(z[2]);
    float h  = sigf(z[3]) * tanhf(cn);
    cst2[e] = cn;
    const int row = 32 * wave + 16 * e + ri;
    X[(size_t)row * XSTR + hoff + 4 * g + hc] = f2bf(h);
  }
}

// ---------------------------------------------------------------------------
// Persistent kernel (PLAIN launch; co-resident by construction: 32KB LDS,
// <=512 VGPR -> every CU hosts >=1 WG, grid 256 = capacity; R1 flat-poll
// barrier working proves all-256 co-residency). WG g owns h-cols [4g,4g+4)
// of every layer (16 z-cols = 4 hcols x 4 gates; B-row for tile col n is
// 1024*(n>>2) + 4g + (n&3)). Waves K-split 4-way; all weights VGPR-resident
// (loaded once); c-state in registers.
//
// Barrier schedule: gbar2 (L1->L2), gbar3 (L2->L3), gbar4 (L3->dec) every
// step; gbar1 (dec(t-1)->L1(t)) ONLY on self-fed steps (pattern(t)==false,
// t>0) — on ground-truth steps x(t) comes straight from seq/XGT.
// ---------------------------------------------------------------------------
__global__ __launch_bounds__(256, 1) void persist(
    const unsigned short* __restrict__ WL1, const unsigned short* __restrict__ WL2,
    const unsigned short* __restrict__ WL3, const unsigned short* __restrict__ WDEC,
    const float* __restrict__ BS, unsigned short* __restrict__ X,
    unsigned* __restrict__ flags,
    const void* __restrict__ seq, const void* __restrict__ decb,
    void* __restrict__ outp, const unsigned short* __restrict__ XGT,
    const int* __restrict__ gtp, const int* __restrict__ condp)
{
  const int g = blockIdx.x;
  const int tid = threadIdx.x, wave = tid >> 6, lane = tid & 63;
  const int l15 = lane & 15, quad = lane >> 4;
  const bool bf = probe_bf16((const unsigned int*)seq);
  int gt = gtp[0]; int per = gt + condp[0]; if (per < 1) per = 1;
  unsigned budget = 20000000u;   // watchdog: total poll iters per wave

  // ---- XCD registration + one-time global rendezvous ----
  __shared__ unsigned s_rank;
  unsigned xcd;
  asm volatile("s_getreg_b32 %0, hwreg(HW_REG_XCC_ID)" : "=s"(xcd));
  xcd &= 7u;
  if (tid == 0) {
    s_rank = __hip_atomic_fetch_add(flags + XCNT_OFF + xcd, 1u,
                                    __ATOMIC_RELAXED, __HIP_MEMORY_SCOPE_AGENT);
    __hip_atomic_fetch_add(flags + GREG_OFF, 1u,
                           __ATOMIC_RELEASE, __HIP_MEMORY_SCOPE_AGENT);
  }
  __syncthreads();
  const unsigned rank = s_rank;
  if (wave == 0 && lane == 0) {
    while (__hip_atomic_load(flags + GREG_OFF, __ATOMIC_ACQUIRE,
                             __HIP_MEMORY_SCOPE_AGENT) < 256u) {
      if (budget == 0) break;
      --budget; __builtin_amdgcn_s_sleep(4);
    }
  }
  __syncthreads();
  const unsigned NX = ld_agent(flags + XCNT_OFF + xcd);
  unsigned amask = 0;
  #pragma unroll
  for (int k = 0; k < 8; ++k)
    amask |= (ld_agent(flags + XCNT_OFF + k) > 0u ? 1u : 0u) << k;

  // ---- weight fragments (VGPR-resident for the whole kernel) ----
  const int br = 1024 * (l15 >> 2) + 4 * g + (l15 & 3);
  v8s w1f[10], w2f[16], w3f[16], wdf[8];
  {
    const unsigned short* p = WL1 + (size_t)br * 1280 + 320 * wave + 8 * quad;
    #pragma unroll
    for (int c = 0; c < 10; ++c) w1f[c] = *(const v8s*)(p + 32 * c);
  }
  {
    const unsigned short* p = WL2 + (size_t)br * 2048 + 512 * wave + 8 * quad;
    #pragma unroll
    for (int c = 0; c < 16; ++c) w2f[c] = *(const v8s*)(p + 32 * c);
  }
  {
    const unsigned short* p = WL3 + (size_t)br * 2048 + 512 * wave + 8 * quad;
    #pragma unroll
    for (int c = 0; c < 16; ++c) w3f[c] = *(const v8s*)(p + 32 * c);
  }
  const int dm = g / 11, dn = g - dm * 11;
  if (g < 88) {
    const unsigned short* p = WDEC + (size_t)(16 * dn + l15) * 1024 + 256 * wave + 8 * quad;
    #pragma unroll
    for (int c = 0; c < 8; ++c) wdf[c] = *(const v8s*)(p + 32 * c);
  } else {
    #pragma unroll
    for (int c = 0; c < 8; ++c) wdf[c] = (v8s){0, 0, 0, 0, 0, 0, 0, 0};
  }
  float bsr[3][4];
  #pragma unroll
  for (int l = 0; l < 3; ++l)
    #pragma unroll
    for (int gm = 0; gm < 4; ++gm)
      bsr[l][gm] = BS[4096 * l + 1024 * gm + 4 * g + (lane & 3)];
  float dbv = 0.f;
  if (g < 88) { int col = 16 * dn + l15; if (col < CDIM) dbv = getv(decb, bf, col); }

  float cst1[2] = {0.f, 0.f}, cst2v[2] = {0.f, 0.f}, cst3[2] = {0.f, 0.f};
  __shared__ float lred[8192];                       // [4 waves][8 tiles][16][16]
  const unsigned short* Xb = X + (size_t)l15 * XSTR + 8 * quad;   // lane A-base
  unsigned bgen = 0;
  v4f acc[8];

  for (int t = 0; t < TSTEPS; ++t) {
    const int p_ = t & 1, q_ = p_ ^ 1;
    const bool pt = (t % per) < gt;                  // ground-truth step?
    if (t > 0 && !pt)
      gbarH(flags, xcd, rank, NX, amask, ++bgen, wave, lane, budget);

    // ---- L1 ----
    if (pt && wave == 0) {
      // wave0's K-slice covers the x-cols: chains 0..7 read seq directly
      // (no barrier dependency on dec), chains 8..9 read h1(t-1) from X.
      #pragma unroll
      for (int i = 0; i < 8; ++i) acc[i] = (v4f){0.f, 0.f, 0.f, 0.f};
      if (XGT) {
        const unsigned short* xb = XGT + ((size_t)t * 128 + l15) * 256 + 8 * quad;
        #pragma unroll
        for (int c = 0; c < 8; ++c) {
          #pragma unroll
          for (int m = 0; m < 8; ++m) {
            v8s a = *(const v8s*)(xb + 32 * c + (size_t)(16 * m) * 256);
            acc[m] = __builtin_amdgcn_mfma_f32_16x16x32_bf16(a, w1f[c], acc[m], 0, 0, 0);
          }
        }
      } else {
        #pragma unroll
        for (int c = 0; c < 8; ++c) {
          const int col0 = 32 * c + 8 * quad;
          #pragma unroll
          for (int m = 0; m < 8; ++m) {
            const size_t so = (size_t)(l15 + 16 * m) * SEQB + (size_t)t * CDIM;
            v8s a;
            #pragma unroll
            for (int j = 0; j < 8; ++j) {
              const int cc = col0 + j;
              unsigned short hv = 0;
              if (cc < CDIM)
                hv = bf ? ((const unsigned short*)seq)[so + cc]
                        : f2bf(((const float*)seq)[so + cc]);
              a[j] = (short)hv;
            }
            acc[m] = __builtin_amdgcn_mfma_f32_16x16x32_bf16(a, w1f[c], acc[m], 0, 0, 0);
          }
        }
      }
      #pragma unroll
      for (int c = 8; c < 10; ++c) {
        const unsigned short* ap = Xb + (256 + 1024 * q_) + (32 * c - 256);
        #pragma unroll
        for (int m = 0; m < 8; ++m) {
          v8s a = *(const v8s*)(ap + (size_t)(16 * m) * XSTR);
          acc[m] = __builtin_amdgcn_mfma_f32_16x16x32_bf16(a, w1f[c], acc[m], 0, 0, 0);
        }
      }
    } else {
      mfma_phase<10>(w1f, Xb, 0, 256, 256 + 1024 * q_, 320 * wave, acc);
    }
    lstm_epilogue(acc, lred, wave, lane, bsr[0], cst1, X, 256 + 1024 * p_, g);

    gbarH(flags, xcd, rank, NX, amask, ++bgen, wave, lane, budget);
    mfma_phase<16>(w2f, Xb, 256 + 1024 * p_, 1024, 2304 + 1024 * q_, 512 * wave, acc);
    lstm_epilogue(acc, lred, wave, lane, bsr[1], cst2v, X, 2304 + 1024 * p_, g);

    gbarH(flags, xcd, rank, NX, amask, ++bgen, wave, lane, budget);
    mfma_phase<16>(w3f, Xb, 2304 + 1024 * p_, 1024, 4352 + 1024 * q_, 512 * wave, acc);
    lstm_epilogue(acc, lred, wave, lane, bsr[2], cst3, X, 4352 + 1024 * p_, g);

    gbarH(flags, xcd, rank, NX, amask, ++bgen, wave, lane, budget);  // L3->dec
    if (g < 88) {
      v4f da = (v4f){0.f, 0.f, 0.f, 0.f};
      const unsigned short* ap = X + (size_t)(16 * dm + l15) * XSTR
                               + (4352 + 1024 * p_) + 256 * wave + 8 * quad;
      #pragma unroll
      for (int c = 0; c < 8; ++c) {
        v8s a = *(const v8s*)(ap + 32 * c);
        da = __builtin_amdgcn_mfma_f32_16x16x32_bf16(a, wdf[c], da, 0, 0, 0);
      }
      float* myp = lred + wave * 2048;
      #pragma unroll
      for (int j = 0; j < 4; ++j)
        myp[l15 * 16 + ((4 * quad + j) ^ ((l15 >> 1) & 3))] = da[j];
      __syncthreads();
      if (wave == 0) {
        const int col = 16 * dn + l15;
        const bool pnext = ((t + 1) % per) < gt;
        #pragma unroll
        for (int e = 0; e < 4; ++e) {
          const int r = 4 * e + quad;
          float v = dbv;
          #pragma unroll
          for (int w2 = 0; w2 < 4; ++w2)
            v += lred[w2 * 2048 + l15 * 16 + (r ^ ((l15 >> 1) & 3))];
          if (col < CDIM) {
            const int brow = 16 * dm + r;
            const size_t oidx = (size_t)brow * SEQB + (size_t)t * CDIM + col;
            if (bf) ((unsigned short*)outp)[oidx] = f2bf(v);
            else    ((float*)outp)[oidx] = v;
            // Self-fed next frame only: ground-truth frames are read
            // straight from seq/XGT by L1, so no X writeback needed.
            if (t < TSTEPS - 1 && !pnext)
              X[(size_t)brow * XSTR + col] = f2bf(v);
          }
        }
      }
      __syncthreads();   // protect lred: next L1 epilogue may follow without
                         // an intervening gbar (skipped on gt steps)
    }
  }
}

// ---------------------------------------------------------------------------
// Workspace (bytes, total ~62.9 MB; XGT used only if ws_size permits):
//   X     @ 0         : [128][6400] bf16          (1,638,400)
//   BS    @ 1638400   : [3][4096] fp32            (49,152)
//   FLAGS @ 1687552   : [4096] u32                (16,384)
//   WL1   @ 1703936   : [4096][1280] bf16         (10,485,760)
//   WL2   @ 12189696  : [4096][2048] bf16         (16,777,216)
//   WL3   @ 28966912  : [4096][2048] bf16         (16,777,216)
//   WDEC  @ 45744128  : [176][1024] bf16          (360,448)
//   XGT   @ 46104576  : [256][128][256] bf16      (16,777,216, optional)
// ---------------------------------------------------------------------------
extern "C" void kernel_launch(void* const* d_in, const int* in_sizes, int n_in,
                              void* d_out, int out_size, void* d_ws, size_t ws_size,
                              hipStream_t stream) {
  const void* seq  = d_in[0];
  const void* wih1 = d_in[1];  const void* whh1 = d_in[2];
  const void* bih1 = d_in[3];  const void* bhh1 = d_in[4];
  const void* wih2 = d_in[5];  const void* whh2 = d_in[6];
  const void* bih2 = d_in[7];  const void* bhh2 = d_in[8];
  const void* wih3 = d_in[9];  const void* whh3 = d_in[10];
  const void* bih3 = d_in[11]; const void* bhh3 = d_in[12];
  const void* decw = d_in[13]; const void* decb = d_in[14];
  const int* gtp   = (const int*)d_in[15];
  const int* condp = (const int*)d_in[16];

  char* ws = (char*)d_ws;
  unsigned short* X    = (unsigned short*)(ws + 0);
  float*          BS   = (float*)(ws + 1638400);
  unsigned*       FLAGS= (unsigned*)(ws + 1687552);
  unsigned short* WL1  = (unsigned short*)(ws + 1703936);
  unsigned short* WL2  = (unsigned short*)(ws + 12189696);
  unsigned short* WL3  = (unsigned short*)(ws + 28966912);
  unsigned short* WDEC = (unsigned short*)(ws + 45744128);
  unsigned short* XGT  = (ws_size >= (size_t)46104576 + (size_t)16777216)
                       ? (unsigned short*)(ws + 46104576) : (unsigned short*)0;

  init_kernel<<<2048, 256, 0, stream>>>(seq, wih1, whh1, bih1, bhh1,
                                        wih2, whh2, bih2, bhh2,
                                        wih3, whh3, bih3, bhh3, decw,
                                        X, BS, FLAGS, WL1, WL2, WL3, WDEC,
                                        XGT, gtp, condp);

  persist<<<256, 256, 0, stream>>>(WL1, WL2, WL3, WDEC, BS, X, FLAGS,
                                   seq, decb, d_out, XGT, gtp, condp);
}

// Round 4
// 16299.294 us; speedup vs baseline: 1.9059x; 1.3011x over previous
//
#include <hip/hip_runtime.h>
#include <math.h>

#define TSTEPS 256
#define CDIM 171
#define XSTR 6400          // 256 (padded x) + 6*1024 (h1,h1',h2,h2',h3,h3')
#define SEQB (TSTEPS*CDIM)

// FLAGS region layout (u32 indices)
#define ARR_OFF   0        // [8][256] per-XCD arrival flags (xcd*256 + rank)
#define GF_OFF    2048     // [8] cross-XCD leader flags, stride 64 (256B pad)
#define REL_OFF   2560     // [8] per-XCD release words, stride 64
#define XCNT_OFF  3072     // [8] per-XCD WG counts
#define GREG_OFF  3080     // [1] global registration count
#define ARR2_OFF  4096     // [8][256] per-XCD copy-done flags
#define NFLAGS    8192

typedef short v8s __attribute__((ext_vector_type(8)));
typedef float v4f __attribute__((ext_vector_type(4)));
typedef unsigned int v4u __attribute__((ext_vector_type(4)));

static __device__ __forceinline__ unsigned short f2bf(float f) {
  unsigned int u = __float_as_uint(f);
  u += 0x7fffu + ((u >> 16) & 1u);          // RTNE
  return (unsigned short)(u >> 16);
}
static __device__ __forceinline__ float bf2f(unsigned short h) {
  return __uint_as_float(((unsigned int)h) << 16);
}
static __device__ __forceinline__ float sigf(float x) { return 1.0f / (1.0f + expf(-x)); }

// dtype probe (verified earlier): bf16 pairs put a bf16 exponent in bits[14:7]
// of each u32; genuine fp32 puts uniform mantissa bits there.
static __device__ __forceinline__ bool probe_bf16(const unsigned int* w) {
  int c = 0;
  #pragma unroll
  for (int i = 0; i < 8; ++i) {
    unsigned e = (w[i] >> 7) & 0xFFu;
    c += (e >= 90u && e <= 145u) ? 1 : 0;
  }
  return c == 8;
}
static __device__ __forceinline__ float getv(const void* p, bool bf, size_t i) {
  return bf ? bf2f(((const unsigned short*)p)[i]) : ((const float*)p)[i];
}

static __device__ __forceinline__ unsigned ld_agent(const unsigned* p) {
  return __hip_atomic_load(p, __ATOMIC_RELAXED, __HIP_MEMORY_SCOPE_AGENT);
}
static __device__ __forceinline__ void st_agent(unsigned* p, unsigned v) {
  __hip_atomic_store(p, v, __ATOMIC_RELAXED, __HIP_MEMORY_SCOPE_AGENT);
}
// 2B write-through store (sc0 sc1): h-state goes straight to the MALL
// coherence point; vmcnt(0) at the next __syncthreads is the release.
static __device__ __forceinline__ void st_short_sys(unsigned short* p, unsigned short v) {
  asm volatile("global_store_short %0, %1, off sc0 sc1"
               :: "v"(p), "v"((unsigned)v) : "memory");
}
// 16B bypass load (sc0 sc1): reads the MALL directly (never stale L1/L2).
static __device__ __forceinline__ v4u ld_b128_sys(const unsigned short* p) {
  v4u v;
  asm volatile("global_load_dwordx4 %0, %1, off sc0 sc1\n\ts_waitcnt vmcnt(0)"
               : "=v"(v) : "v"(p) : "memory");
  return v;
}

// ---------------------------------------------------------------------------
// init: seed X + all 8 XCD replicas, bias sums, zero flags, repack weights:
//   WL1 [4096][1280] = [wih1 padded to 256 | whh1]
//   WL2/WL3 [4096][2048] = [wih | whh]
//   WDEC [176][1024] = dec_w zero-padded rows
//   XR   [8][128][XSTR] per-XCD activation replicas (seeded = X image)
//   XGT  [256][128][256] = bf16 ground-truth x (optional, ws-permitting)
// ---------------------------------------------------------------------------
__global__ __launch_bounds__(256) void init_kernel(
    const void* seq, const void* wih1, const void* whh1,
    const void* bih1, const void* bhh1,
    const void* wih2, const void* whh2, const void* bih2, const void* bhh2,
    const void* wih3, const void* whh3, const void* bih3, const void* bhh3,
    const void* decw,
    unsigned short* __restrict__ X, float* __restrict__ BS,
    unsigned* __restrict__ flags,
    unsigned short* __restrict__ WL1, unsigned short* __restrict__ WL2,
    unsigned short* __restrict__ WL3, unsigned short* __restrict__ WDEC,
    unsigned short* __restrict__ XR, unsigned short* __restrict__ XGT,
    const int* __restrict__ gtp, const int* __restrict__ condp)
{
  const int tid = blockIdx.x * 256 + threadIdx.x;
  const int NT = 2048 * 256;
  const bool bfm = probe_bf16((const unsigned int*)seq);
  int gt = gtp[0];
  const bool p0 = 0 < gt;

  for (int i = tid; i < 128 * XSTR; i += NT) {
    int b = i / XSTR, c = i - b * XSTR;
    unsigned short v = 0;
    if (c < CDIM && p0) v = f2bf(getv(seq, bfm, (size_t)b * SEQB + c));
    X[i] = v;
  }
  for (int i = tid; i < 8 * 128 * XSTR; i += NT) {   // replicas = X image
    int r = i % (128 * XSTR);
    int b = r / XSTR, c = r - b * XSTR;
    unsigned short v = 0;
    if (c < CDIM && p0) v = f2bf(getv(seq, bfm, (size_t)b * SEQB + c));
    XR[i] = v;
  }
  const void* bis[3] = {bih1, bih2, bih3};
  const void* bhs[3] = {bhh1, bhh2, bhh3};
  for (int i = tid; i < 3 * 4096; i += NT) {
    int l = i >> 12, n = i & 4095;
    BS[i] = getv(bis[l], bfm, n) + getv(bhs[l], bfm, n);
  }
  for (int i = tid; i < NFLAGS; i += NT) flags[i] = 0u;
  for (int i = tid; i < 4096 * 1280; i += NT) {
    int r = i / 1280, c = i - r * 1280;
    float v;
    if (c < CDIM)      v = getv(wih1, bfm, (size_t)r * CDIM + c);
    else if (c < 256)  v = 0.f;
    else               v = getv(whh1, bfm, (size_t)r * 1024 + (c - 256));
    WL1[i] = f2bf(v);
  }
  for (int i = tid; i < 4096 * 2048; i += NT) {
    int r = i >> 11, c = i & 2047;
    size_t o = (size_t)r * 1024 + (c & 1023);
    WL2[i] = f2bf((c < 1024) ? getv(wih2, bfm, o) : getv(whh2, bfm, o));
    WL3[i] = f2bf((c < 1024) ? getv(wih3, bfm, o) : getv(whh3, bfm, o));
  }
  for (int i = tid; i < 176 * 1024; i += NT) {
    int r = i >> 10, c = i & 1023;
    WDEC[i] = (r < CDIM) ? f2bf(getv(decw, bfm, (size_t)r * 1024 + c)) : (unsigned short)0;
  }
  if (XGT) {
    for (int i = tid; i < TSTEPS * 128 * 256; i += NT) {
      int t = i >> 15, b = (i >> 8) & 127, c = i & 255;
      unsigned short v = 0;
      if (c < CDIM) v = f2bf(getv(seq, bfm, (size_t)b * SEQB + (size_t)t * CDIM + c));
      XGT[i] = v;
    }
  }
}

// ---------------------------------------------------------------------------
// Fence-free global barrier (R4): NO wbl2, NO L2 inv — release is the
// write-through h-stores (sc0 sc1) drained by the entry __syncthreads'
// implicit vmcnt(0); all flag traffic is agent-scope atomics through MALL.
// Hierarchical: leader (rank 0 of its physical XCD via HW_REG_XCC_ID)
// aggregates its XCD's arrivals, posts gf, waits all-XCD gf, posts rel.
// WATCHDOG: budget caps poll iterations (deadlock -> fast wrong-answer
// finish with counters, not a harness timeout).
// ---------------------------------------------------------------------------
static __device__ __forceinline__ void gbar_nf(
    unsigned* fl, unsigned xcd, unsigned rank, unsigned NX, unsigned amask,
    unsigned G, int wave, int lane, unsigned& budget)
{
  __syncthreads();                    // vmcnt(0): my sc1 h-stores are in MALL
  if (threadIdx.x == 0) st_agent(fl + ARR_OFF + xcd * 256 + rank, G);
  if (wave == 0) {
    if (rank == 0) {
      const unsigned* ab = fl + ARR_OFF + xcd * 256;
      for (;;) {
        unsigned ok = 1u;
        #pragma unroll
        for (int k = 0; k < 4; ++k) {
          unsigned r = (unsigned)lane + 64u * k;
          if (r < NX) ok &= (ld_agent(ab + r) >= G) ? 1u : 0u;
        }
        if (__all((int)ok)) break;
        if (budget == 0) break;
        --budget; __builtin_amdgcn_s_sleep(1);
      }
      st_agent(fl + GF_OFF + xcd * 64, G);
      for (;;) {
        unsigned ok = 1u;
        if (lane < 8 && ((amask >> lane) & 1u))
          ok = (ld_agent(fl + GF_OFF + (unsigned)lane * 64) >= G) ? 1u : 0u;
        if (__all((int)ok)) break;
        if (budget == 0) break;
        --budget; __builtin_amdgcn_s_sleep(1);
      }
      st_agent(fl + REL_OFF + xcd * 64, G);
    } else {
      unsigned* rp = fl + REL_OFF + xcd * 64;
      for (;;) {
        unsigned v = ld_agent(rp);
        if (__all((int)(v >= G))) break;
        if (budget == 0) break;
        --budget; __builtin_amdgcn_s_sleep(1);
      }
    }
  }
  __syncthreads();
}

// Replica copy: this XCD's WGs cooperatively pull the just-written bank from
// MALL (sc0 sc1 bypass) into the XCD-private replica (plain write-back
// stores -> local L2). chunk = 16 B; row = c>>rowshift, col = (c&mask)*8.
static __device__ __forceinline__ void xcopy(
    unsigned short* __restrict__ dst, const unsigned short* __restrict__ src,
    int hoff, int nchunks, int rowshift, unsigned rank, unsigned NX, int tid)
{
  const int mask = (1 << rowshift) - 1;
  for (unsigned c = rank * 256u + (unsigned)tid; c < (unsigned)nchunks;
       c += NX * 256u) {
    int row = (int)(c >> rowshift);
    size_t off = (size_t)row * XSTR + hoff + ((size_t)(c & mask) << 3);
    v4u v = ld_b128_sys(src + off);
    *(v4u*)(dst + off) = v;
  }
}

// Intra-XCD copy-done barrier: agent flags (hang-proof), then ONE L1-only
// buffer_inv per CU (cheap, not a tag walk of L2) so subsequent plain loads
// of the replica can't hit stale L1 lines from 2 steps ago.
static __device__ __forceinline__ void xbar(
    unsigned* fl, unsigned xcd, unsigned rank, unsigned NX,
    unsigned G, int wave, int lane, unsigned& budget)
{
  __syncthreads();                    // vmcnt(0): my replica stores are in L2
  if (threadIdx.x == 0) st_agent(fl + ARR2_OFF + xcd * 256 + rank, G);
  if (wave == 0) {
    const unsigned* ab = fl + ARR2_OFF + xcd * 256;
    for (;;) {
      unsigned ok = 1u;
      #pragma unroll
      for (int k = 0; k < 4; ++k) {
        unsigned r = (unsigned)lane + 64u * k;
        if (r < NX) ok &= (ld_agent(ab + r) >= G) ? 1u : 0u;
      }
      if (__all((int)ok)) break;
      if (budget == 0) break;
      --budget; __builtin_amdgcn_s_sleep(1);
    }
    asm volatile("buffer_inv" ::: "memory");       // L1-only invalidate
  }
  __syncthreads();
}

// MFMA phase: wave's K-slice against register-resident B frags, 8 M-tiles.
// A cols map through [a0 | a1] split at bnd (activation double-banking).
// A-reads are PLAIN loads from the XCD-local replica (L2-warm).
template<int NCH>
static __device__ __forceinline__ void mfma_phase(
    const v8s* wf, const unsigned short* __restrict__ Xb,
    int a0, int bnd, int a1, int kbase, v4f* acc)
{
  #pragma unroll
  for (int i = 0; i < 8; ++i) acc[i] = (v4f){0.f, 0.f, 0.f, 0.f};
  #pragma unroll
  for (int c = 0; c < NCH; ++c) {
    const int acol = kbase + 32 * c;
    const int xcol = (acol < bnd) ? (a0 + acol) : (a1 + acol - bnd);
    const unsigned short* ap = Xb + xcol;
    #pragma unroll
    for (int m = 0; m < 8; ++m) {
      v8s a = *(const v8s*)(ap + (size_t)(16 * m) * XSTR);
      acc[m] = __builtin_amdgcn_mfma_f32_16x16x32_bf16(a, wf[c], acc[m], 0, 0, 0);
    }
  }
}

// LDS 4-way K-reduce + register-local gate math + write-through bf16 h store.
// lred: col-major XOR swizzle — stores and reads both 2 lanes/bank (free).
// NOTE: no trailing __syncthreads — every call site is followed by a barrier
// whose leading __syncthreads provides the lred WAR protection.
static __device__ __forceinline__ void lstm_epilogue(
    v4f* acc, float* lred, int wave, int lane,
    const float* bs4, float* cst2,
    unsigned short* __restrict__ X, int hoff, int g)
{
  const int l15 = lane & 15, quad = lane >> 4;
  float* myp = lred + wave * 2048;
  #pragma unroll
  for (int m = 0; m < 8; ++m)
    #pragma unroll
    for (int j = 0; j < 4; ++j)
      myp[m * 256 + l15 * 16 + ((4 * quad + j) ^ ((l15 >> 1) & 3))] = acc[m][j];
  __syncthreads();
  const int ri = lane >> 2, hc = lane & 3;
  #pragma unroll
  for (int e = 0; e < 2; ++e) {
    const int m = 2 * wave + e;
    float z[4];
    #pragma unroll
    for (int k = 0; k < 4; ++k) z[k] = bs4[k];
    #pragma unroll
    for (int w2 = 0; w2 < 4; ++w2) {
      const float* pp = lred + w2 * 2048 + m * 256;
      #pragma unroll
      for (int k = 0; k < 4; ++k) {
        const int col = hc + 4 * k;
        z[k] += pp[col * 16 + (ri ^ ((col >> 1) & 3))];
      }
    }
    float cn = sigf(z[1]) * cst2[e] + sigf(z[0]) * tanhf(z[2]);
    float h  = sigf(z[3]) * tanhf(cn);
    cst2[e] = cn;
    const int row = 32 * wave + 16 * e + ri;
    st_short_sys(X + (size_t)row * XSTR + hoff + 4 * g + hc, f2bf(h));
  }
}

// ---------------------------------------------------------------------------
// Persistent kernel. WG g owns h-cols [4g,4g+4) of every layer; waves K-split
// 4-way; weights VGPR-resident; c-state in registers. Cross-WG h exchange:
// write-through to MALL -> fence-free global barrier -> per-XCD replica copy
// -> intra-XCD barrier + L1 inv -> compute from local replica. ZERO L2
// wbl2/inv walks in the whole main loop.
// Sync slots/step: 3 always (post-L1/L2/L3) + 1 on self-fed steps (post-dec).
// ---------------------------------------------------------------------------
__global__ __launch_bounds__(256, 1) void persist(
    const unsigned short* __restrict__ WL1, const unsigned short* __restrict__ WL2,
    const unsigned short* __restrict__ WL3, const unsigned short* __restrict__ WDEC,
    const float* __restrict__ BS, unsigned short* __restrict__ X,
    unsigned* __restrict__ flags, unsigned short* __restrict__ XR,
    const void* __restrict__ seq, const void* __restrict__ decb,
    void* __restrict__ outp, const unsigned short* __restrict__ XGT,
    const int* __restrict__ gtp, const int* __restrict__ condp)
{
  const int g = blockIdx.x;
  const int tid = threadIdx.x, wave = tid >> 6, lane = tid & 63;
  const int l15 = lane & 15, quad = lane >> 4;
  const bool bf = probe_bf16((const unsigned int*)seq);
  int gt = gtp[0]; int per = gt + condp[0]; if (per < 1) per = 1;
  unsigned budget = 20000000u;   // watchdog: total poll iters per wave

  // ---- XCD registration + one-time global rendezvous ----
  __shared__ unsigned s_rank;
  unsigned xcd;
  asm volatile("s_getreg_b32 %0, hwreg(HW_REG_XCC_ID)" : "=s"(xcd));
  xcd &= 7u;
  if (tid == 0) {
    s_rank = __hip_atomic_fetch_add(flags + XCNT_OFF + xcd, 1u,
                                    __ATOMIC_RELAXED, __HIP_MEMORY_SCOPE_AGENT);
    __hip_atomic_fetch_add(flags + GREG_OFF, 1u,
                           __ATOMIC_RELEASE, __HIP_MEMORY_SCOPE_AGENT);
  }
  __syncthreads();
  const unsigned rank = s_rank;
  if (wave == 0 && lane == 0) {
    while (__hip_atomic_load(flags + GREG_OFF, __ATOMIC_ACQUIRE,
                             __HIP_MEMORY_SCOPE_AGENT) < 256u) {
      if (budget == 0) break;
      --budget; __builtin_amdgcn_s_sleep(4);
    }
  }
  __syncthreads();
  const unsigned NX = ld_agent(flags + XCNT_OFF + xcd);
  unsigned amask = 0;
  #pragma unroll
  for (int k = 0; k < 8; ++k)
    amask |= (ld_agent(flags + XCNT_OFF + k) > 0u ? 1u : 0u) << k;

  unsigned short* XRb = XR + (size_t)xcd * (128 * XSTR);   // my XCD's replica

  // ---- weight fragments (VGPR-resident for the whole kernel) ----
  const int br = 1024 * (l15 >> 2) + 4 * g + (l15 & 3);
  v8s w1f[10], w2f[16], w3f[16], wdf[8];
  {
    const unsigned short* p = WL1 + (size_t)br * 1280 + 320 * wave + 8 * quad;
    #pragma unroll
    for (int c = 0; c < 10; ++c) w1f[c] = *(const v8s*)(p + 32 * c);
  }
  {
    const unsigned short* p = WL2 + (size_t)br * 2048 + 512 * wave + 8 * quad;
    #pragma unroll
    for (int c = 0; c < 16; ++c) w2f[c] = *(const v8s*)(p + 32 * c);
  }
  {
    const unsigned short* p = WL3 + (size_t)br * 2048 + 512 * wave + 8 * quad;
    #pragma unroll
    for (int c = 0; c < 16; ++c) w3f[c] = *(const v8s*)(p + 32 * c);
  }
  const int dm = g / 11, dn = g - dm * 11;
  if (g < 88) {
    const unsigned short* p = WDEC + (size_t)(16 * dn + l15) * 1024 + 256 * wave + 8 * quad;
    #pragma unroll
    for (int c = 0; c < 8; ++c) wdf[c] = *(const v8s*)(p + 32 * c);
  } else {
    #pragma unroll
    for (int c = 0; c < 8; ++c) wdf[c] = (v8s){0, 0, 0, 0, 0, 0, 0, 0};
  }
  float bsr[3][4];
  #pragma unroll
  for (int l = 0; l < 3; ++l)
    #pragma unroll
    for (int gm = 0; gm < 4; ++gm)
      bsr[l][gm] = BS[4096 * l + 1024 * gm + 4 * g + (lane & 3)];
  float dbv = 0.f;
  if (g < 88) { int col = 16 * dn + l15; if (col < CDIM) dbv = getv(decb, bf, col); }

  float cst1[2] = {0.f, 0.f}, cst2v[2] = {0.f, 0.f}, cst3[2] = {0.f, 0.f};
  __shared__ float lred[8192];                       // [4 waves][8 tiles][16][16]
  const unsigned short* Xb = XRb + (size_t)l15 * XSTR + 8 * quad;  // lane A-base
  unsigned bgen = 0;
  v4f acc[8];

  for (int t = 0; t < TSTEPS; ++t) {
    const int p_ = t & 1, q_ = p_ ^ 1;
    const bool pt = (t % per) < gt;                  // ground-truth step?
    if (t > 0 && !pt) {                              // dec(t-1) x -> replicas
      gbar_nf(flags, xcd, rank, NX, amask, ++bgen, wave, lane, budget);
      xcopy(XRb, X, 0, 4096, 5, rank, NX, tid);
      xbar(flags, xcd, rank, NX, bgen, wave, lane, budget);
    }

    // ---- L1 ----
    if (pt && wave == 0) {
      // wave0's K-slice covers the x-cols: chains 0..7 read XGT/seq directly
      // (no barrier dependency on dec), chains 8..9 read h1(t-1) replica.
      #pragma unroll
      for (int i = 0; i < 8; ++i) acc[i] = (v4f){0.f, 0.f, 0.f, 0.f};
      if (XGT) {
        const unsigned short* xb = XGT + ((size_t)t * 128 + l15) * 256 + 8 * quad;
        #pragma unroll
        for (int c = 0; c < 8; ++c) {
          #pragma unroll
          for (int m = 0; m < 8; ++m) {
            v8s a = *(const v8s*)(xb + 32 * c + (size_t)(16 * m) * 256);
            acc[m] = __builtin_amdgcn_mfma_f32_16x16x32_bf16(a, w1f[c], acc[m], 0, 0, 0);
          }
        }
      } else {
        #pragma unroll
        for (int c = 0; c < 8; ++c) {
          const int col0 = 32 * c + 8 * quad;
          #pragma unroll
          for (int m = 0; m < 8; ++m) {
            const size_t so = (size_t)(l15 + 16 * m) * SEQB + (size_t)t * CDIM;
            v8s a;
            #pragma unroll
            for (int j = 0; j < 8; ++j) {
              const int cc = col0 + j;
              unsigned short hv = 0;
              if (cc < CDIM)
                hv = bf ? ((const unsigned short*)seq)[so + cc]
                        : f2bf(((const float*)seq)[so + cc]);
              a[j] = (short)hv;
            }
            acc[m] = __builtin_amdgcn_mfma_f32_16x16x32_bf16(a, w1f[c], acc[m], 0, 0, 0);
          }
        }
      }
      #pragma unroll
      for (int c = 8; c < 10; ++c) {
        const unsigned short* ap = Xb + (256 + 1024 * q_) + (32 * c - 256);
        #pragma unroll
        for (int m = 0; m < 8; ++m) {
          v8s a = *(const v8s*)(ap + (size_t)(16 * m) * XSTR);
          acc[m] = __builtin_amdgcn_mfma_f32_16x16x32_bf16(a, w1f[c], acc[m], 0, 0, 0);
        }
      }
    } else {
      mfma_phase<10>(w1f, Xb, 0, 256, 256 + 1024 * q_, 320 * wave, acc);
    }
    lstm_epilogue(acc, lred, wave, lane, bsr[0], cst1, X, 256 + 1024 * p_, g);

    gbar_nf(flags, xcd, rank, NX, amask, ++bgen, wave, lane, budget);
    xcopy(XRb, X, 256 + 1024 * p_, 16384, 7, rank, NX, tid);
    xbar(flags, xcd, rank, NX, bgen, wave, lane, budget);
    mfma_phase<16>(w2f, Xb, 256 + 1024 * p_, 1024, 2304 + 1024 * q_, 512 * wave, acc);
    lstm_epilogue(acc, lred, wave, lane, bsr[1], cst2v, X, 2304 + 1024 * p_, g);

    gbar_nf(flags, xcd, rank, NX, amask, ++bgen, wave, lane, budget);
    xcopy(XRb, X, 2304 + 1024 * p_, 16384, 7, rank, NX, tid);
    xbar(flags, xcd, rank, NX, bgen, wave, lane, budget);
    mfma_phase<16>(w3f, Xb, 2304 + 1024 * p_, 1024, 4352 + 1024 * q_, 512 * wave, acc);
    lstm_epilogue(acc, lred, wave, lane, bsr[2], cst3, X, 4352 + 1024 * p_, g);

    gbar_nf(flags, xcd, rank, NX, amask, ++bgen, wave, lane, budget);  // L3->dec
    xcopy(XRb, X, 4352 + 1024 * p_, 16384, 7, rank, NX, tid);
    xbar(flags, xcd, rank, NX, bgen, wave, lane, budget);
    if (g < 88) {
      v4f da = (v4f){0.f, 0.f, 0.f, 0.f};
      const unsigned short* ap = XRb + (size_t)(16 * dm + l15) * XSTR
                               + (4352 + 1024 * p_) + 256 * wave + 8 * quad;
      #pragma unroll
      for (int c = 0; c < 8; ++c) {
        v8s a = *(const v8s*)(ap + 32 * c);
        da = __builtin_amdgcn_mfma_f32_16x16x32_bf16(a, wdf[c], da, 0, 0, 0);
      }
      float* myp = lred + wave * 2048;
      #pragma unroll
      for (int j = 0; j < 4; ++j)
        myp[l15 * 16 + ((4 * quad + j) ^ ((l15 >> 1) & 3))] = da[j];
      __syncthreads();
      if (wave == 0) {
        const int col = 16 * dn + l15;
        const bool pnext = ((t + 1) % per) < gt;
        #pragma unroll
        for (int e = 0; e < 4; ++e) {
          const int r = 4 * e + quad;
          float v = dbv;
          #pragma unroll
          for (int w2 = 0; w2 < 4; ++w2)
            v += lred[w2 * 2048 + l15 * 16 + (r ^ ((l15 >> 1) & 3))];
          if (col < CDIM) {
            const int brow = 16 * dm + r;
            const size_t oidx = (size_t)brow * SEQB + (size_t)t * CDIM + col;
            if (bf) ((unsigned short*)outp)[oidx] = f2bf(v);
            else    ((float*)outp)[oidx] = v;
            // Self-fed next frame only (gt frames come from XGT/seq):
            // write-through so next step's x-copy sees it in MALL.
            if (t < TSTEPS - 1 && !pnext)
              st_short_sys(X + (size_t)brow * XSTR + col, f2bf(v));
          }
        }
      }
      __syncthreads();   // protect lred: next L1 epilogue may follow without
                         // an intervening barrier (gt steps skip the dec sync)
    }
  }
}

// ---------------------------------------------------------------------------
// Workspace (bytes; XGT used only if ws_size permits, required total 59.3MB):
//   X     @ 0         : [128][6400] bf16          (1,638,400)
//   BS    @ 1638400   : [3][4096] fp32            (49,152)
//   FLAGS @ 1687552   : [8192] u32                (32,768)
//   XR    @ 1720320   : [8][128][6400] bf16       (13,107,200)
//   WL1   @ 14827520  : [4096][1280] bf16         (10,485,760)
//   WL2   @ 25313280  : [4096][2048] bf16         (16,777,216)
//   WL3   @ 42090496  : [4096][2048] bf16         (16,777,216)
//   WDEC  @ 58867712  : [176][1024] bf16          (360,448)
//   XGT   @ 59228160  : [256][128][256] bf16      (16,777,216, optional)
// ---------------------------------------------------------------------------
extern "C" void kernel_launch(void* const* d_in, const int* in_sizes, int n_in,
                              void* d_out, int out_size, void* d_ws, size_t ws_size,
                              hipStream_t stream) {
  const void* seq  = d_in[0];
  const void* wih1 = d_in[1];  const void* whh1 = d_in[2];
  const void* bih1 = d_in[3];  const void* bhh1 = d_in[4];
  const void* wih2 = d_in[5];  const void* whh2 = d_in[6];
  const void* bih2 = d_in[7];  const void* bhh2 = d_in[8];
  const void* wih3 = d_in[9];  const void* whh3 = d_in[10];
  const void* bih3 = d_in[11]; const void* bhh3 = d_in[12];
  const void* decw = d_in[13]; const void* decb = d_in[14];
  const int* gtp   = (const int*)d_in[15];
  const int* condp = (const int*)d_in[16];

  char* ws = (char*)d_ws;
  unsigned short* X    = (unsigned short*)(ws + 0);
  float*          BS   = (float*)(ws + 1638400);
  unsigned*       FLAGS= (unsigned*)(ws + 1687552);
  unsigned short* XR   = (unsigned short*)(ws + 1720320);
  unsigned short* WL1  = (unsigned short*)(ws + 14827520);
  unsigned short* WL2  = (unsigned short*)(ws + 25313280);
  unsigned short* WL3  = (unsigned short*)(ws + 42090496);
  unsigned short* WDEC = (unsigned short*)(ws + 58867712);
  unsigned short* XGT  = (ws_size >= (size_t)59228160 + (size_t)16777216)
                       ? (unsigned short*)(ws + 59228160) : (unsigned short*)0;

  init_kernel<<<2048, 256, 0, stream>>>(seq, wih1, whh1, bih1, bhh1,
                                        wih2, whh2, bih2, bhh2,
                                        wih3, whh3, bih3, bhh3, decw,
                                        X, BS, FLAGS, WL1, WL2, WL3, WDEC,
                                        XR, XGT, gtp, condp);

  persist<<<256, 256, 0, stream>>>(WL1, WL2, WL3, WDEC, BS, X, FLAGS, XR,
                                   seq, decb, d_out, XGT, gtp, condp);
}

// Round 5
// 16056.677 us; speedup vs baseline: 1.9347x; 1.0151x over previous
//
#include <hip/hip_runtime.h>
#include <math.h>

#define TSTEPS 256
#define CDIM 171
#define XSTR 6400          // 256 (padded x) + 6*1024 (h1,h1',h2,h2',h3,h3')
#define SEQB (TSTEPS*CDIM)

// FLAGS region layout (u32 indices)
#define ARR_OFF   0        // [8][256] per-XCD arrival flags (xcd*256 + rank)
#define GF_OFF    2048     // [8] cross-XCD leader flags, stride 64 (256B pad)
#define REL_OFF   2560     // [8] per-XCD release words, stride 64
#define XCNT_OFF  3072     // [8] per-XCD WG counts
#define GREG_OFF  3080     // [1] global registration count
#define ARR2_OFF  4096     // [8][256] per-XCD local-barrier flags
#define NFLAGS    8192

typedef short v8s __attribute__((ext_vector_type(8)));
typedef float v4f __attribute__((ext_vector_type(4)));

static __device__ __forceinline__ unsigned short f2bf(float f) {
  unsigned int u = __float_as_uint(f);
  u += 0x7fffu + ((u >> 16) & 1u);          // RTNE
  return (unsigned short)(u >> 16);
}
static __device__ __forceinline__ float bf2f(unsigned short h) {
  return __uint_as_float(((unsigned int)h) << 16);
}
static __device__ __forceinline__ float sigf(float x) { return 1.0f / (1.0f + expf(-x)); }

// dtype probe (verified earlier): bf16 pairs put a bf16 exponent in bits[14:7]
// of each u32; genuine fp32 puts uniform mantissa bits there.
static __device__ __forceinline__ bool probe_bf16(const unsigned int* w) {
  int c = 0;
  #pragma unroll
  for (int i = 0; i < 8; ++i) {
    unsigned e = (w[i] >> 7) & 0xFFu;
    c += (e >= 90u && e <= 145u) ? 1 : 0;
  }
  return c == 8;
}
static __device__ __forceinline__ float getv(const void* p, bool bf, size_t i) {
  return bf ? bf2f(((const unsigned short*)p)[i]) : ((const float*)p)[i];
}

// AGENT scope (sc1 only -> terminates at MALL, never forced to HBM).
// R4 ERRATA: hand-rolled "sc0 sc1" was SYSTEM scope -> HBM round trips
// (FETCH_SIZE 884MB, WRITE_SIZE 2.4GB). Compiler atomics emit the proven
// agent encoding (same as the working R3/R4 flag traffic).
static __device__ __forceinline__ unsigned ld_agent(const unsigned* p) {
  return __hip_atomic_load(p, __ATOMIC_RELAXED, __HIP_MEMORY_SCOPE_AGENT);
}
static __device__ __forceinline__ void st_agent(unsigned* p, unsigned v) {
  __hip_atomic_store(p, v, __ATOMIC_RELAXED, __HIP_MEMORY_SCOPE_AGENT);
}
static __device__ __forceinline__ void st_agent_us(unsigned short* p, unsigned short v) {
  __hip_atomic_store(p, v, __ATOMIC_RELAXED, __HIP_MEMORY_SCOPE_AGENT);
}

// ---------------------------------------------------------------------------
// init: seed X + all 8 XCD replicas, bias sums, zero flags, repack weights:
//   WL1 [4096][1280] = [wih1 padded to 256 | whh1]
//   WL2/WL3 [4096][2048] = [wih | whh]
//   WDEC [176][1024] = dec_w zero-padded rows
//   XR   [8][128][XSTR] per-XCD activation replicas (seeded = X image)
//   XGT  [256][128][256] = bf16 ground-truth x (optional, ws-permitting)
// ---------------------------------------------------------------------------
__global__ __launch_bounds__(256) void init_kernel(
    const void* seq, const void* wih1, const void* whh1,
    const void* bih1, const void* bhh1,
    const void* wih2, const void* whh2, const void* bih2, const void* bhh2,
    const void* wih3, const void* whh3, const void* bih3, const void* bhh3,
    const void* decw,
    unsigned short* __restrict__ X, float* __restrict__ BS,
    unsigned* __restrict__ flags,
    unsigned short* __restrict__ WL1, unsigned short* __restrict__ WL2,
    unsigned short* __restrict__ WL3, unsigned short* __restrict__ WDEC,
    unsigned short* __restrict__ XR, unsigned short* __restrict__ XGT,
    const int* __restrict__ gtp, const int* __restrict__ condp)
{
  const int tid = blockIdx.x * 256 + threadIdx.x;
  const int NT = 2048 * 256;
  const bool bfm = probe_bf16((const unsigned int*)seq);
  int gt = gtp[0];
  const bool p0 = 0 < gt;

  for (int i = tid; i < 128 * XSTR; i += NT) {
    int b = i / XSTR, c = i - b * XSTR;
    unsigned short v = 0;
    if (c < CDIM && p0) v = f2bf(getv(seq, bfm, (size_t)b * SEQB + c));
    X[i] = v;
  }
  for (int i = tid; i < 8 * 128 * XSTR; i += NT) {   // replicas = X image
    int r = i % (128 * XSTR);
    int b = r / XSTR, c = r - b * XSTR;
    unsigned short v = 0;
    if (c < CDIM && p0) v = f2bf(getv(seq, bfm, (size_t)b * SEQB + c));
    XR[i] = v;
  }
  const void* bis[3] = {bih1, bih2, bih3};
  const void* bhs[3] = {bhh1, bhh2, bhh3};
  for (int i = tid; i < 3 * 4096; i += NT) {
    int l = i >> 12, n = i & 4095;
    BS[i] = getv(bis[l], bfm, n) + getv(bhs[l], bfm, n);
  }
  for (int i = tid; i < NFLAGS; i += NT) flags[i] = 0u;
  for (int i = tid; i < 4096 * 1280; i += NT) {
    int r = i / 1280, c = i - r * 1280;
    float v;
    if (c < CDIM)      v = getv(wih1, bfm, (size_t)r * CDIM + c);
    else if (c < 256)  v = 0.f;
    else               v = getv(whh1, bfm, (size_t)r * 1024 + (c - 256));
    WL1[i] = f2bf(v);
  }
  for (int i = tid; i < 4096 * 2048; i += NT) {
    int r = i >> 11, c = i & 2047;
    size_t o = (size_t)r * 1024 + (c & 1023);
    WL2[i] = f2bf((c < 1024) ? getv(wih2, bfm, o) : getv(whh2, bfm, o));
    WL3[i] = f2bf((c < 1024) ? getv(wih3, bfm, o) : getv(whh3, bfm, o));
  }
  for (int i = tid; i < 176 * 1024; i += NT) {
    int r = i >> 10, c = i & 1023;
    WDEC[i] = (r < CDIM) ? f2bf(getv(decw, bfm, (size_t)r * 1024 + c)) : (unsigned short)0;
  }
  if (XGT) {
    for (int i = tid; i < TSTEPS * 128 * 256; i += NT) {
      int t = i >> 15, b = (i >> 8) & 127, c = i & 255;
      unsigned short v = 0;
      if (c < CDIM) v = f2bf(getv(seq, bfm, (size_t)b * SEQB + (size_t)t * CDIM + c));
      XGT[i] = v;
    }
  }
}

// ---------------------------------------------------------------------------
// Fence-free global barrier: NO wbl2, NO L2 inv. Release = the agent-scope
// write-through h-stores drained by the entry __syncthreads' implicit
// vmcnt(0); all flag traffic is agent atomics through MALL. Hierarchical:
// leader (rank 0 of its physical XCD via HW_REG_XCC_ID) aggregates arrivals,
// posts gf, waits all-XCD gf, posts rel. WATCHDOG: budget caps poll iters
// (deadlock -> fast wrong-answer finish with counters, not a timeout).
// ---------------------------------------------------------------------------
static __device__ __forceinline__ void gbar_nf(
    unsigned* fl, unsigned xcd, unsigned rank, unsigned NX, unsigned amask,
    unsigned G, int wave, int lane, unsigned& budget)
{
  __syncthreads();                    // vmcnt(0): my agent h-stores are in MALL
  if (threadIdx.x == 0) st_agent(fl + ARR_OFF + xcd * 256 + rank, G);
  if (wave == 0) {
    if (rank == 0) {
      const unsigned* ab = fl + ARR_OFF + xcd * 256;
      for (;;) {
        unsigned ok = 1u;
        #pragma unroll
        for (int k = 0; k < 4; ++k) {
          unsigned r = (unsigned)lane + 64u * k;
          if (r < NX) ok &= (ld_agent(ab + r) >= G) ? 1u : 0u;
        }
        if (__all((int)ok)) break;
        if (budget == 0) break;
        --budget; __builtin_amdgcn_s_sleep(1);
      }
      st_agent(fl + GF_OFF + xcd * 64, G);
      for (;;) {
        unsigned ok = 1u;
        if (lane < 8 && ((amask >> lane) & 1u))
          ok = (ld_agent(fl + GF_OFF + (unsigned)lane * 64) >= G) ? 1u : 0u;
        if (__all((int)ok)) break;
        if (budget == 0) break;
        --budget; __builtin_amdgcn_s_sleep(1);
      }
      st_agent(fl + REL_OFF + xcd * 64, G);
    } else {
      unsigned* rp = fl + REL_OFF + xcd * 64;
      for (;;) {
        unsigned v = ld_agent(rp);
        if (__all((int)(v >= G))) break;
        if (budget == 0) break;
        --budget; __builtin_amdgcn_s_sleep(1);
      }
    }
  }
  __syncthreads();
}

// Replica copy: this XCD's WGs pull the just-written 256KB h-bank from MALL
// (agent dword loads, 8 in flight per thread = ONE latency, coalesced) into
// the XCD-private replica (plain write-back stores -> local L2).
static __device__ __forceinline__ void xcopy(
    unsigned short* __restrict__ dst, const unsigned short* __restrict__ src,
    int hoff, unsigned rank, unsigned NX, int tid)
{
  if (NX == 32u) {                      // 8192 threads, 65536 dwords: 8/thread
    const unsigned d0 = rank * 256u + (unsigned)tid;
    unsigned vv[8];
    #pragma unroll
    for (int k = 0; k < 8; ++k) {
      unsigned d = d0 + 8192u * k;
      size_t off = (size_t)(d >> 9) * XSTR + hoff + ((size_t)(d & 511u) << 1);
      vv[k] = ld_agent((const unsigned*)(src + off));
    }
    #pragma unroll
    for (int k = 0; k < 8; ++k) {
      unsigned d = d0 + 8192u * k;
      size_t off = (size_t)(d >> 9) * XSTR + hoff + ((size_t)(d & 511u) << 1);
      *(unsigned*)(dst + off) = vv[k];
    }
  } else {
    for (unsigned d = rank * 256u + (unsigned)tid; d < 65536u; d += NX * 256u) {
      size_t off = (size_t)(d >> 9) * XSTR + hoff + ((size_t)(d & 511u) << 1);
      *(unsigned*)(dst + off) = ld_agent((const unsigned*)(src + off));
    }
  }
}

// Intra-XCD barrier: agent flags (hang-proof), then ONE L1-only buffer_inv
// per CU (cheap, not an L2 tag walk) so plain loads of the replica can't hit
// stale L1 lines from 2 steps ago.
static __device__ __forceinline__ void xbar(
    unsigned* fl, unsigned xcd, unsigned rank, unsigned NX,
    unsigned G, int wave, int lane, unsigned& budget)
{
  __syncthreads();                    // vmcnt(0): my replica stores are in L2
  if (threadIdx.x == 0) st_agent(fl + ARR2_OFF + xcd * 256 + rank, G);
  if (wave == 0) {
    const unsigned* ab = fl + ARR2_OFF + xcd * 256;
    for (;;) {
      unsigned ok = 1u;
      #pragma unroll
      for (int k = 0; k < 4; ++k) {
        unsigned r = (unsigned)lane + 64u * k;
        if (r < NX) ok &= (ld_agent(ab + r) >= G) ? 1u : 0u;
      }
      if (__all((int)ok)) break;
      if (budget == 0) break;
      --budget; __builtin_amdgcn_s_sleep(1);
    }
    asm volatile("buffer_inv" ::: "memory");       // L1-only invalidate
  }
  __syncthreads();
}

// MFMA phase: wave's K-slice against register-resident B frags, 8 M-tiles.
// A cols map through [a0 | a1] split at bnd (activation double-banking).
// A-reads are PLAIN loads from the XCD-local replica (L2-warm).
template<int NCH>
static __device__ __forceinline__ void mfma_phase(
    const v8s* wf, const unsigned short* __restrict__ Xb,
    int a0, int bnd, int a1, int kbase, v4f* acc)
{
  #pragma unroll
  for (int i = 0; i < 8; ++i) acc[i] = (v4f){0.f, 0.f, 0.f, 0.f};
  #pragma unroll
  for (int c = 0; c < NCH; ++c) {
    const int acol = kbase + 32 * c;
    const int xcol = (acol < bnd) ? (a0 + acol) : (a1 + acol - bnd);
    const unsigned short* ap = Xb + xcol;
    #pragma unroll
    for (int m = 0; m < 8; ++m) {
      v8s a = *(const v8s*)(ap + (size_t)(16 * m) * XSTR);
      acc[m] = __builtin_amdgcn_mfma_f32_16x16x32_bf16(a, wf[c], acc[m], 0, 0, 0);
    }
  }
}

// LDS 4-way K-reduce + register-local gate math + agent bf16 h store to MALL.
// lred: col-major XOR swizzle — stores and reads both 2 lanes/bank (free).
// NOTE: no trailing __syncthreads — every call site is followed by a barrier
// whose leading __syncthreads provides the lred WAR protection.
static __device__ __forceinline__ void lstm_epilogue(
    v4f* acc, float* lred, int wave, int lane,
    const float* bs4, float* cst2,
    unsigned short* __restrict__ X, int hoff, int g)
{
  const int l15 = lane & 15, quad = lane >> 4;
  float* myp = lred + wave * 2048;
  #pragma unroll
  for (int m = 0; m < 8; ++m)
    #pragma unroll
    for (int j = 0; j < 4; ++j)
      myp[m * 256 + l15 * 16 + ((4 * quad + j) ^ ((l15 >> 1) & 3))] = acc[m][j];
  __syncthreads();
  const int ri = lane >> 2, hc = lane & 3;
  #pragma unroll
  for (int e = 0; e < 2; ++e) {
    const int m = 2 * wave + e;
    float z[4];
    #pragma unroll
    for (int k = 0; k < 4; ++k) z[k] = bs4[k];
    #pragma unroll
    for (int w2 = 0; w2 < 4; ++w2) {
      const float* pp = lred + w2 * 2048 + m * 256;
      #pragma unroll
      for (int k = 0; k < 4; ++k) {
        const int col = hc + 4 * k;
        z[k] += pp[col * 16 + (ri ^ ((col >> 1) & 3))];
      }
    }
    float cn = sigf(z[1]) * cst2[e] + sigf(z[0]) * tanhf(z[2]);
    float h  = sigf(z[3]) * tanhf(cn);
    cst2[e] = cn;
    const int row = 32 * wave + 16 * e + ri;
    st_agent_us(X + (size_t)row * XSTR + hoff + 4 * g + hc, f2bf(h));
  }
}

// One 16x16 decoder tile: MFMA over h3 (replica) x WDEC (L2-streamed),
// lred reduce, optional outp write / local-replica x write. Uniform per WG.
static __device__ __forceinline__ void dec_tile(
    int dm2, int dn2, const unsigned short* __restrict__ WDEC,
    const unsigned short* __restrict__ XRb, int p_, float* lred,
    int wave, int lane, int l15, int quad,
    const void* __restrict__ decb, bool bf, bool wout, bool wx,
    void* __restrict__ outp, int t)
{
  v4f da = (v4f){0.f, 0.f, 0.f, 0.f};
  const unsigned short* wp = WDEC + (size_t)(16 * dn2 + l15) * 1024 + 256 * wave + 8 * quad;
  const unsigned short* ap = XRb + (size_t)(16 * dm2 + l15) * XSTR
                           + (4352 + 1024 * p_) + 256 * wave + 8 * quad;
  #pragma unroll
  for (int c = 0; c < 8; ++c) {
    v8s a = *(const v8s*)(ap + 32 * c);
    v8s w = *(const v8s*)(wp + 32 * c);
    da = __builtin_amdgcn_mfma_f32_16x16x32_bf16(a, w, da, 0, 0, 0);
  }
  float* myp = lred + wave * 2048;
  #pragma unroll
  for (int j = 0; j < 4; ++j)
    myp[l15 * 16 + ((4 * quad + j) ^ ((l15 >> 1) & 3))] = da[j];
  __syncthreads();
  if (wave == 0) {
    const int col = 16 * dn2 + l15;
    float dbv2 = (col < CDIM) ? getv(decb, bf, col) : 0.f;
    #pragma unroll
    for (int e = 0; e < 4; ++e) {
      const int r = 4 * e + quad;
      float v = dbv2;
      #pragma unroll
      for (int w2 = 0; w2 < 4; ++w2)
        v += lred[w2 * 2048 + l15 * 16 + (r ^ ((l15 >> 1) & 3))];
      if (col < CDIM) {
        const int brow = 16 * dm2 + r;
        if (wout) {
          const size_t oidx = (size_t)brow * SEQB + (size_t)t * CDIM + col;
          if (bf) ((unsigned short*)outp)[oidx] = f2bf(v);
          else    ((float*)outp)[oidx] = v;
        }
        // self-fed next frame into the LOCAL replica (plain store, local L2)
        if (wx) *(unsigned short*)((unsigned short*)XRb
                  + (size_t)brow * XSTR + col) = f2bf(v);
      }
    }
  }
  __syncthreads();   // lred WAR (next tile / next L1 epilogue)
}

// ---------------------------------------------------------------------------
// Persistent kernel. WG g owns h-cols [4g,4g+4) of every layer; waves K-split
// 4-way; L1/L2/L3 weights VGPR-resident; c-state in registers. Cross-WG h
// exchange: agent store to MALL -> fence-free global barrier -> per-XCD
// replica copy -> intra-XCD barrier + L1 inv -> compute from local replica.
// ZERO L2 wbl2/inv walks in the main loop.
//
// Decoder (R5): on self-fed-next steps EVERY XCD computes the FULL decoder
// (rank-strided tiles, weights streamed from L2) into its own replica ->
// dec->L1 exchange is XCD-LOCAL (xbar only, no 4th global slot). On
// gt-next steps only WGs g<88 compute dec (output only), no sync after.
// Global syncs: 3/step uniformly (768 total, was 896).
// ---------------------------------------------------------------------------
__global__ __launch_bounds__(256, 1) void persist(
    const unsigned short* __restrict__ WL1, const unsigned short* __restrict__ WL2,
    const unsigned short* __restrict__ WL3, const unsigned short* __restrict__ WDEC,
    const float* __restrict__ BS, unsigned short* __restrict__ X,
    unsigned* __restrict__ flags, unsigned short* __restrict__ XR,
    const void* __restrict__ seq, const void* __restrict__ decb,
    void* __restrict__ outp, const unsigned short* __restrict__ XGT,
    const int* __restrict__ gtp, const int* __restrict__ condp)
{
  const int g = blockIdx.x;
  const int tid = threadIdx.x, wave = tid >> 6, lane = tid & 63;
  const int l15 = lane & 15, quad = lane >> 4;
  const bool bf = probe_bf16((const unsigned int*)seq);
  int gt = gtp[0]; int per = gt + condp[0]; if (per < 1) per = 1;
  unsigned budget = 20000000u;   // watchdog: total poll iters per wave

  // ---- XCD registration + one-time global rendezvous ----
  __shared__ unsigned s_rank;
  unsigned xcd;
  asm volatile("s_getreg_b32 %0, hwreg(HW_REG_XCC_ID)" : "=s"(xcd));
  xcd &= 7u;
  if (tid == 0) {
    s_rank = __hip_atomic_fetch_add(flags + XCNT_OFF + xcd, 1u,
                                    __ATOMIC_RELAXED, __HIP_MEMORY_SCOPE_AGENT);
    __hip_atomic_fetch_add(flags + GREG_OFF, 1u,
                           __ATOMIC_RELEASE, __HIP_MEMORY_SCOPE_AGENT);
  }
  __syncthreads();
  const unsigned rank = s_rank;
  if (wave == 0 && lane == 0) {
    while (__hip_atomic_load(flags + GREG_OFF, __ATOMIC_ACQUIRE,
                             __HIP_MEMORY_SCOPE_AGENT) < 256u) {
      if (budget == 0) break;
      --budget; __builtin_amdgcn_s_sleep(4);
    }
  }
  __syncthreads();
  const unsigned NX = ld_agent(flags + XCNT_OFF + xcd);
  unsigned amask = 0;
  #pragma unroll
  for (int k = 0; k < 8; ++k)
    amask |= (ld_agent(flags + XCNT_OFF + k) > 0u ? 1u : 0u) << k;
  const unsigned owner = (unsigned)__builtin_ctz(amask | 0x100u);
  const bool isown = (xcd == owner);

  unsigned short* XRb = XR + (size_t)xcd * (128 * XSTR);   // my XCD's replica

  // ---- weight fragments (VGPR-resident for the whole kernel) ----
  const int br = 1024 * (l15 >> 2) + 4 * g + (l15 & 3);
  v8s w1f[10], w2f[16], w3f[16];
  {
    const unsigned short* p = WL1 + (size_t)br * 1280 + 320 * wave + 8 * quad;
    #pragma unroll
    for (int c = 0; c < 10; ++c) w1f[c] = *(const v8s*)(p + 32 * c);
  }
  {
    const unsigned short* p = WL2 + (size_t)br * 2048 + 512 * wave + 8 * quad;
    #pragma unroll
    for (int c = 0; c < 16; ++c) w2f[c] = *(const v8s*)(p + 32 * c);
  }
  {
    const unsigned short* p = WL3 + (size_t)br * 2048 + 512 * wave + 8 * quad;
    #pragma unroll
    for (int c = 0; c < 16; ++c) w3f[c] = *(const v8s*)(p + 32 * c);
  }
  const int dm = g / 11, dn = g - dm * 11;
  float bsr[3][4];
  #pragma unroll
  for (int l = 0; l < 3; ++l)
    #pragma unroll
    for (int gm = 0; gm < 4; ++gm)
      bsr[l][gm] = BS[4096 * l + 1024 * gm + 4 * g + (lane & 3)];

  float cst1[2] = {0.f, 0.f}, cst2v[2] = {0.f, 0.f}, cst3[2] = {0.f, 0.f};
  __shared__ float lred[8192];                       // [4 waves][8 tiles][16][16]
  const unsigned short* Xb = XRb + (size_t)l15 * XSTR + 8 * quad;  // lane A-base
  unsigned bgen = 0;
  v4f acc[8];

  for (int t = 0; t < TSTEPS; ++t) {
    const int p_ = t & 1, q_ = p_ ^ 1;
    const bool pt = (t % per) < gt;                  // ground-truth step?

    // ---- L1 ---- (self-fed x was written into the LOCAL replica by dec)
    if (pt && wave == 0) {
      // wave0's K-slice covers the x-cols: chains 0..7 read XGT/seq directly
      // (no dependency on dec), chains 8..9 read h1(t-1) replica.
      #pragma unroll
      for (int i = 0; i < 8; ++i) acc[i] = (v4f){0.f, 0.f, 0.f, 0.f};
      if (XGT) {
        const unsigned short* xb = XGT + ((size_t)t * 128 + l15) * 256 + 8 * quad;
        #pragma unroll
        for (int c = 0; c < 8; ++c) {
          #pragma unroll
          for (int m = 0; m < 8; ++m) {
            v8s a = *(const v8s*)(xb + 32 * c + (size_t)(16 * m) * 256);
            acc[m] = __builtin_amdgcn_mfma_f32_16x16x32_bf16(a, w1f[c], acc[m], 0, 0, 0);
          }
        }
      } else {
        #pragma unroll
        for (int c = 0; c < 8; ++c) {
          const int col0 = 32 * c + 8 * quad;
          #pragma unroll
          for (int m = 0; m < 8; ++m) {
            const size_t so = (size_t)(l15 + 16 * m) * SEQB + (size_t)t * CDIM;
            v8s a;
            #pragma unroll
            for (int j = 0; j < 8; ++j) {
              const int cc = col0 + j;
              unsigned short hv = 0;
              if (cc < CDIM)
                hv = bf ? ((const unsigned short*)seq)[so + cc]
                        : f2bf(((const float*)seq)[so + cc]);
              a[j] = (short)hv;
            }
            acc[m] = __builtin_amdgcn_mfma_f32_16x16x32_bf16(a, w1f[c], acc[m], 0, 0, 0);
          }
        }
      }
      #pragma unroll
      for (int c = 8; c < 10; ++c) {
        const unsigned short* ap = Xb + (256 + 1024 * q_) + (32 * c - 256);
        #pragma unroll
        for (int m = 0; m < 8; ++m) {
          v8s a = *(const v8s*)(ap + (size_t)(16 * m) * XSTR);
          acc[m] = __builtin_amdgcn_mfma_f32_16x16x32_bf16(a, w1f[c], acc[m], 0, 0, 0);
        }
      }
    } else {
      mfma_phase<10>(w1f, Xb, 0, 256, 256 + 1024 * q_, 320 * wave, acc);
    }
    lstm_epilogue(acc, lred, wave, lane, bsr[0], cst1, X, 256 + 1024 * p_, g);

    gbar_nf(flags, xcd, rank, NX, amask, ++bgen, wave, lane, budget);
    xcopy(XRb, X, 256 + 1024 * p_, rank, NX, tid);
    xbar(flags, xcd, rank, NX, bgen, wave, lane, budget);
    mfma_phase<16>(w2f, Xb, 256 + 1024 * p_, 1024, 2304 + 1024 * q_, 512 * wave, acc);
    lstm_epilogue(acc, lred, wave, lane, bsr[1], cst2v, X, 2304 + 1024 * p_, g);

    gbar_nf(flags, xcd, rank, NX, amask, ++bgen, wave, lane, budget);
    xcopy(XRb, X, 2304 + 1024 * p_, rank, NX, tid);
    xbar(flags, xcd, rank, NX, bgen, wave, lane, budget);
    mfma_phase<16>(w3f, Xb, 2304 + 1024 * p_, 1024, 4352 + 1024 * q_, 512 * wave, acc);
    lstm_epilogue(acc, lred, wave, lane, bsr[2], cst3, X, 4352 + 1024 * p_, g);

    gbar_nf(flags, xcd, rank, NX, amask, ++bgen, wave, lane, budget);  // L3->dec
    xcopy(XRb, X, 4352 + 1024 * p_, rank, NX, tid);
    xbar(flags, xcd, rank, NX, bgen, wave, lane, budget);

    // ---- decoder ----
    const bool pnext = ((t + 1) % per) < gt;
    const bool needx = (t < TSTEPS - 1) && !pnext;   // uniform across grid
    if (needx) {
      // every XCD computes the full decoder into its own replica x-region
      for (unsigned tt = rank; tt < 88u; tt += NX) {
        int dm2 = (int)(tt / 11u), dn2 = (int)(tt - (unsigned)dm2 * 11u);
        dec_tile(dm2, dn2, WDEC, XRb, p_, lred, wave, lane, l15, quad,
                 decb, bf, isown, true, outp, t);
      }
      ++bgen;                                        // dec->L1 is XCD-local
      xbar(flags, xcd, rank, NX, bgen, wave, lane, budget);
    } else if (g < 88) {
      dec_tile(dm, dn, WDEC, XRb, p_, lred, wave, lane, l15, quad,
               decb, bf, true, false, outp, t);
    }
  }
}

// ---------------------------------------------------------------------------
// Workspace (bytes; XGT used only if ws_size permits, required total 59.3MB):
//   X     @ 0         : [128][6400] bf16          (1,638,400)
//   BS    @ 1638400   : [3][4096] fp32            (49,152)
//   FLAGS @ 1687552   : [8192] u32                (32,768)
//   XR    @ 1720320   : [8][128][6400] bf16       (13,107,200)
//   WL1   @ 14827520  : [4096][1280] bf16         (10,485,760)
//   WL2   @ 25313280  : [4096][2048] bf16         (16,777,216)
//   WL3   @ 42090496  : [4096][2048] bf16         (16,777,216)
//   WDEC  @ 58867712  : [176][1024] bf16          (360,448)
//   XGT   @ 59228160  : [256][128][256] bf16      (16,777,216, optional)
// ---------------------------------------------------------------------------
extern "C" void kernel_launch(void* const* d_in, const int* in_sizes, int n_in,
                              void* d_out, int out_size, void* d_ws, size_t ws_size,
                              hipStream_t stream) {
  const void* seq  = d_in[0];
  const void* wih1 = d_in[1];  const void* whh1 = d_in[2];
  const void* bih1 = d_in[3];  const void* bhh1 = d_in[4];
  const void* wih2 = d_in[5];  const void* whh2 = d_in[6];
  const void* bih2 = d_in[7];  const void* bhh2 = d_in[8];
  const void* wih3 = d_in[9];  const void* whh3 = d_in[10];
  const void* bih3 = d_in[11]; const void* bhh3 = d_in[12];
  const void* decw = d_in[13]; const void* decb = d_in[14];
  const int* gtp   = (const int*)d_in[15];
  const int* condp = (const int*)d_in[16];

  char* ws = (char*)d_ws;
  unsigned short* X    = (unsigned short*)(ws + 0);
  float*          BS   = (float*)(ws + 1638400);
  unsigned*       FLAGS= (unsigned*)(ws + 1687552);
  unsigned short* XR   = (unsigned short*)(ws + 1720320);
  unsigned short* WL1  = (unsigned short*)(ws + 14827520);
  unsigned short* WL2  = (unsigned short*)(ws + 25313280);
  unsigned short* WL3  = (unsigned short*)(ws + 42090496);
  unsigned short* WDEC = (unsigned short*)(ws + 58867712);
  unsigned short* XGT  = (ws_size >= (size_t)59228160 + (size_t)16777216)
                       ? (unsigned short*)(ws + 59228160) : (unsigned short*)0;

  init_kernel<<<2048, 256, 0, stream>>>(seq, wih1, whh1, bih1, bhh1,
                                        wih2, whh2, bih2, bhh2,
                                        wih3, whh3, bih3, bhh3, decw,
                                        X, BS, FLAGS, WL1, WL2, WL3, WDEC,
                                        XR, XGT, gtp, condp);

  persist<<<256, 256, 0, stream>>>(WL1, WL2, WL3, WDEC, BS, X, FLAGS, XR,
                                   seq, decb, d_out, XGT, gtp, condp);
}